// Round 3
// baseline (1701.713 us; speedup 1.0000x reference)
//
#include <hip/hip_runtime.h>
#include <hip/hip_bf16.h>
#include <math.h>
#include <stdint.h>

#define SEQL 4096
#define NH 16
#define CDIM 3072
#define DPROJ 3088
#define DMODEL 1024

typedef __hip_bfloat16 bf16;

__device__ inline void store_val(float* p, float v) { *p = v; }
__device__ inline void store_val(bf16* p, float v) { *p = __float2bfloat16(v); }

// ---------------- generic f32 GEMM: C[M,N] = A[M,K] @ B[N,K]^T ----------------
template <typename TOUT>
__global__ __launch_bounds__(256) void gemm_nt(const float* __restrict__ A,
                                               const float* __restrict__ B,
                                               TOUT* __restrict__ C,
                                               int M, int N, int K) {
  __shared__ float As[16][68];
  __shared__ float Bs[16][68];
  int tx = threadIdx.x;
  int bm = blockIdx.y * 64, bn = blockIdx.x * 64;
  int tm = (tx >> 4) << 2, tn = (tx & 15) << 2;
  float acc[4][4] = {};
  for (int k0 = 0; k0 < K; k0 += 16) {
    for (int i = tx; i < 1024; i += 256) {
      int m = i >> 4, k = i & 15;
      As[k][m] = (bm + m < M) ? A[(size_t)(bm + m) * K + k0 + k] : 0.f;
      Bs[k][m] = (bn + m < N) ? B[(size_t)(bn + m) * K + k0 + k] : 0.f;
    }
    __syncthreads();
#pragma unroll
    for (int k = 0; k < 16; ++k) {
      float a0[4], b0[4];
#pragma unroll
      for (int j = 0; j < 4; ++j) { a0[j] = As[k][tm + j]; b0[j] = Bs[k][tn + j]; }
#pragma unroll
      for (int i = 0; i < 4; ++i)
#pragma unroll
        for (int j = 0; j < 4; ++j) acc[i][j] = fmaf(a0[i], b0[j], acc[i][j]);
    }
    __syncthreads();
  }
  for (int i = 0; i < 4; ++i) {
    int m = bm + tm + i;
    if (m >= M) break;
    for (int j = 0; j < 4; ++j) {
      int n = bn + tn + j;
      if (n < N) store_val(&C[(size_t)m * N + n], acc[i][j]);
    }
  }
}

// ---------------- intra-chunk SSD with fused depthwise conv ----------------
// grid: bid = b*1024 + c*16 + h (2048 blocks), 256 threads
__global__ __launch_bounds__(256) void ssd_intra(
    const bf16* __restrict__ xw, const float* __restrict__ cw,
    const float* __restrict__ cb, const float* __restrict__ wbase,
    float* __restrict__ Ybuf, float* __restrict__ states,
    float* __restrict__ norm_diag, float* __restrict__ sdo_g,
    float* __restrict__ ndecay, float* __restrict__ Alast) {
  __shared__ float Cs[68][64];      // raw rows 0..66, conv'd rows 0..63; later scores
  __shared__ float Bs[68][65];      // padded: score loop reads column-wise
  __shared__ float Xs[68][64];
  __shared__ float av[64], cums[64], mincs[64], dec[64], sdo_s[64];
  __shared__ float s_nd;
  float (*Sc)[64] = Cs;             // scores alias Cs

  int tid = threadIdx.x;
  int h = blockIdx.x & 15;
  int c = (blockIdx.x >> 4) & 63;
  int b = blockIdx.x >> 10;

  // ---- load raw rows t = c*64-3 .. c*64+63 (67 rows) for the 3 tensors ----
  for (int i = tid; i < 67 * 64; i += 256) {
    int row = i >> 6, n = i & 63;
    int t = c * 64 - 3 + row;
    float vc = 0.f, vb = 0.f, vx = 0.f;
    if (t >= 0) {
      const bf16* r = xw + ((size_t)(b * SEQL + t)) * DPROJ + h * 64 + n;
      vc = __bfloat162float(r[0]);
      vb = __bfloat162float(r[1024]);
      vx = __bfloat162float(r[2048]);
    }
    Cs[row][n] = vc; Bs[row][n] = vb; Xs[row][n] = vx;
  }
  if (tid < 64)
    av[tid] = __bfloat162float(xw[((size_t)(b * SEQL + c * 64 + tid)) * DPROJ + CDIM + h]) * wbase[h];
  __syncthreads();

  // ---- depthwise causal conv(4) into registers, then write back in place ----
  float rc[16], rb[16], rx[16];
  {
    int n = tid & 63;
    const float* wcc = cw + (size_t)(h * 64 + n) * 4;
    const float* wcb = cw + (size_t)(1024 + h * 64 + n) * 4;
    const float* wcx = cw + (size_t)(2048 + h * 64 + n) * 4;
    float bc = cb[h * 64 + n], bb = cb[1024 + h * 64 + n], bx = cb[2048 + h * 64 + n];
#pragma unroll
    for (int q = 0; q < 16; ++q) {
      int l = (tid >> 6) + q * 4;
      rc[q] = fmaf(Cs[l + 3][n], wcc[3], fmaf(Cs[l + 2][n], wcc[2],
               fmaf(Cs[l + 1][n], wcc[1], fmaf(Cs[l][n], wcc[0], bc))));
      rb[q] = fmaf(Bs[l + 3][n], wcb[3], fmaf(Bs[l + 2][n], wcb[2],
               fmaf(Bs[l + 1][n], wcb[1], fmaf(Bs[l][n], wcb[0], bb))));
      rx[q] = fmaf(Xs[l + 3][n], wcx[3], fmaf(Xs[l + 2][n], wcx[2],
               fmaf(Xs[l + 1][n], wcx[1], fmaf(Xs[l][n], wcx[0], bx))));
    }
  }
  __syncthreads();
  {
    int n = tid & 63;
#pragma unroll
    for (int q = 0; q < 16; ++q) {
      int l = (tid >> 6) + q * 4;
      Cs[l][n] = rc[q]; Bs[l][n] = rb[q]; Xs[l][n] = rx[q];
    }
  }
  __syncthreads();

  // ---- cumsum / prefix-min / decay scalars ----
  if (tid == 0) {
    float cum = 0.f, mn = 1e30f, mx = -1e30f;
    for (int l = 0; l < 64; ++l) {
      cum += av[l];
      cums[l] = cum;
      mn = fminf(mn, cum);
      mincs[l] = mn;
      mx = fmaxf(mx, cum);
    }
    float nd = 0.f;
    for (int l = 0; l < 64; ++l) {
      dec[l] = expf(mn - cums[l]);
      nd += dec[l];
      sdo_s[l] = expf(cums[l] - mx);
    }
    s_nd = nd;
  }
  __syncthreads();

  // ---- scores S[l,s] = (C_l . B_s) * exp(minc_l - cum_s), s<=l ----
  float sv[16];
#pragma unroll
  for (int k = 0; k < 16; ++k) {
    int i = tid + (k << 8);
    int l = i >> 6, s = i & 63;
    float v = 0.f;
    if (s <= l) {
      float g = 0.f;
#pragma unroll 8
      for (int n = 0; n < 64; ++n) g = fmaf(Cs[l][n], Bs[s][n], g);
      v = g * expf(mincs[l] - cums[s]);
    }
    sv[k] = v;
  }
  __syncthreads();
#pragma unroll
  for (int k = 0; k < 16; ++k) {
    int i = tid + (k << 8);
    Sc[i >> 6][i & 63] = sv[k];
  }
  __syncthreads();

  if (tid < 64) {
    int l = tid;
    float ndg = 0.f;
    for (int s = 0; s <= l; ++s) ndg += expf(mincs[l] - cums[s]);
    norm_diag[(size_t)blockIdx.x * 64 + l] = ndg;
    sdo_g[(size_t)blockIdx.x * 64 + l] = sdo_s[l];
  }
  if (tid == 0) {
    ndecay[blockIdx.x] = s_nd;
    Alast[((size_t)(b * NH + h)) * 64 + c] = cums[63];
  }

  // ---- Y_diag = S @ X ----
  size_t ybase = ((size_t)(b * SEQL + c * 64)) * DMODEL + h * 64;
  for (int i = tid; i < 4096; i += 256) {
    int l = i >> 6, p = i & 63;
    float y = 0.f;
    for (int s = 0; s <= l; ++s) y = fmaf(Sc[l][s], Xs[s][p], y);
    Ybuf[ybase + (size_t)l * DMODEL + p] = y;
  }
  // ---- chunk states[p,n] = sum_l dec[l]*X[l,p]*B[l,n] ----
  size_t sbase = (size_t)blockIdx.x * 4096;
  for (int i = tid; i < 4096; i += 256) {
    int p = i >> 6, n = i & 63;
    float st = 0.f;
#pragma unroll 8
    for (int l = 0; l < 64; ++l) st = fmaf(dec[l] * Xs[l][p], Bs[l][n], st);
    states[sbase + i] = st;
  }
}

// ---------------- inter-chunk scan (stable, in place: new[z] -> slot z-1) ----------------
// grid: bid = b*16 + h (32 blocks), 256 threads
__global__ __launch_bounds__(256) void ssd_scan(
    const float* __restrict__ Alast, float* __restrict__ states,
    const float* __restrict__ ndecay, float* __restrict__ nd_in) {
  __shared__ float cA[64], cB[64];
  int tid = threadIdx.x;
  int h = blockIdx.x & 15, b = blockIdx.x >> 4;
  if (tid == 0) {
    float cum = 0.f, minc = 0.f, ndR = 0.f;
    nd_in[(b * 64 + 0) * 16 + h] = 0.f;
    for (int z = 1; z < 64; ++z) {
      cum += Alast[(b * NH + h) * 64 + (z - 1)];
      float nm = fminf(minc, cum);
      cA[z] = expf(nm - minc);
      cB[z] = expf(nm - cum);
      minc = nm;
      ndR = cA[z] * ndR + cB[z] * ndecay[(b * 64 + (z - 1)) * 16 + h];
      nd_in[(b * 64 + z) * 16 + h] = ndR;
    }
  }
  __syncthreads();
  float R[16];
#pragma unroll
  for (int j = 0; j < 16; ++j) R[j] = 0.f;
  for (int z = 1; z < 64; ++z) {
    float a = cA[z], w = cB[z];
    size_t slot = ((size_t)(b * 64 + (z - 1)) * 16 + h) * 4096 + tid;
#pragma unroll
    for (int j = 0; j < 16; ++j) {
      float v = states[slot + 256 * j];
      R[j] = a * R[j] + w * v;
      states[slot + 256 * j] = R[j];
    }
  }
}

// ---------------- off-diagonal + combine (conv fused for C tensor) ----------------
__global__ __launch_bounds__(256) void ssd_off(
    const bf16* __restrict__ xw, const float* __restrict__ cw,
    const float* __restrict__ cb, const float* __restrict__ states,
    const float* __restrict__ norm_diag, const float* __restrict__ sdo_g,
    const float* __restrict__ nd_in, float* __restrict__ Ybuf) {
  __shared__ float Cs[68][64];
  __shared__ float Ss[64][65];   // padded (read column-wise over p)
  int tid = threadIdx.x;
  int h = blockIdx.x & 15;
  int c = (blockIdx.x >> 4) & 63;
  int b = blockIdx.x >> 10;

  for (int i = tid; i < 67 * 64; i += 256) {
    int row = i >> 6, n = i & 63;
    int t = c * 64 - 3 + row;
    Cs[row][n] = (t >= 0)
        ? __bfloat162float(xw[((size_t)(b * SEQL + t)) * DPROJ + h * 64 + n])
        : 0.f;
  }
  // scanned state for chunk c sits at slot (b, c-1, h); chunk 0 has zero state
  if (c > 0) {
    size_t sbase = (((size_t)(b * 64 + (c - 1)) * 16 + h)) * 4096;
    for (int i = tid; i < 4096; i += 256) Ss[i >> 6][i & 63] = states[sbase + i];
  } else {
    for (int i = tid; i < 4096; i += 256) Ss[i >> 6][i & 63] = 0.f;
  }
  __syncthreads();

  float rc[16];
  {
    int n = tid & 63;
    const float* wcc = cw + (size_t)(h * 64 + n) * 4;
    float bc = cb[h * 64 + n];
#pragma unroll
    for (int q = 0; q < 16; ++q) {
      int l = (tid >> 6) + q * 4;
      rc[q] = fmaf(Cs[l + 3][n], wcc[3], fmaf(Cs[l + 2][n], wcc[2],
               fmaf(Cs[l + 1][n], wcc[1], fmaf(Cs[l][n], wcc[0], bc))));
    }
  }
  __syncthreads();
  {
    int n = tid & 63;
#pragma unroll
    for (int q = 0; q < 16; ++q) Cs[(tid >> 6) + q * 4][n] = rc[q];
  }
  __syncthreads();

  float ndin = nd_in[blockIdx.x];
  size_t ybase = ((size_t)(b * SEQL + c * 64)) * DMODEL + h * 64;
  for (int i = tid; i < 4096; i += 256) {
    int l = i >> 6, p = i & 63;
    float yo = 0.f;
#pragma unroll 8
    for (int n = 0; n < 64; ++n) yo = fmaf(Cs[l][n], Ss[p][n], yo);
    float sd = sdo_g[(size_t)blockIdx.x * 64 + l];
    float nrm = norm_diag[(size_t)blockIdx.x * 64 + l] + ndin * sd;
    size_t yi = ybase + (size_t)l * DMODEL + p;
    Ybuf[yi] = (Ybuf[yi] + yo * sd) / nrm;
  }
}

extern "C" void kernel_launch(void* const* d_in, const int* in_sizes, int n_in,
                              void* d_out, int out_size, void* d_ws, size_t ws_size,
                              hipStream_t stream) {
  const float* x          = (const float*)d_in[0];
  const float* in_proj_w  = (const float*)d_in[1];
  const float* conv_w     = (const float*)d_in[2];
  const float* conv_b     = (const float*)d_in[3];
  const float* w_base     = (const float*)d_in[4];
  const float* out_proj_w = (const float*)d_in[5];
  float* out = (float*)d_out;

  char* ws = (char*)d_ws;
  size_t off = 0;
  auto alloc = [&](size_t bytes) {
    void* p = ws + off;
    off += (bytes + 255) & ~(size_t)255;
    return p;
  };
  const size_t BT = (size_t)2 * SEQL;                      // 8192
  bf16* xIOw  = (bf16*)alloc(BT * DPROJ * 2);              // 50.6 MB
  float* Ybuf = (float*)alloc(BT * DMODEL * 4);            // 33.6 MB
  float* norm_diag = (float*)alloc((size_t)2048 * 64 * 4); // 0.5 MB
  float* sdo  = (float*)alloc((size_t)2048 * 64 * 4);      // 0.5 MB
  float* ndec = (float*)alloc((size_t)2048 * 4);
  float* Alast = (float*)alloc((size_t)2048 * 4);
  float* nd_in = (float*)alloc((size_t)2048 * 4);
  // total ws usage ~85.2 MB
  // chunk states (2048 x 4096 f32 = 33.6 MB) live in d_out; dead before final GEMM.
  float* states = out;

  // 1) in-projection GEMM (bf16 output)
  gemm_nt<bf16><<<dim3((DPROJ + 63) / 64, BT / 64), 256, 0, stream>>>(
      x, in_proj_w, xIOw, (int)BT, DPROJ, DMODEL);
  // 2) intra-chunk SSD (conv fused)
  ssd_intra<<<2048, 256, 0, stream>>>(xIOw, conv_w, conv_b, w_base,
                                      Ybuf, states, norm_diag, sdo, ndec, Alast);
  // 3) inter-chunk scan (in place on states)
  ssd_scan<<<32, 256, 0, stream>>>(Alast, states, ndec, nd_in);
  // 4) off-diagonal + normalize (conv fused for C)
  ssd_off<<<2048, 256, 0, stream>>>(xIOw, conv_w, conv_b, states,
                                    norm_diag, sdo, nd_in, Ybuf);
  // 5) out-projection GEMM (f32 output to d_out)
  gemm_nt<float><<<dim3(DMODEL / 64, BT / 64), 256, 0, stream>>>(
      Ybuf, out_proj_w, out, (int)BT, DMODEL, DMODEL);
}

// Round 4
// 553.214 us; speedup vs baseline: 3.0761x; 3.0761x over previous
//
#include <hip/hip_runtime.h>
#include <hip/hip_bf16.h>
#include <math.h>
#include <stdint.h>

#define SEQL 4096
#define NH 16
#define CDIM 3072
#define DPROJ 3088
#define DMODEL 1024

typedef __hip_bfloat16 bf16;
typedef __bf16 nbf16;
typedef __attribute__((ext_vector_type(8))) __bf16 bf16x8;
typedef __attribute__((ext_vector_type(4))) float f32x4;

__device__ inline void store_val(float* p, float v) { *p = v; }
__device__ inline void store_val(bf16* p, float v) { *p = __float2bfloat16(v); }

__device__ __forceinline__ void gload_lds16(const void* g, void* l) {
  __builtin_amdgcn_global_load_lds(
      (const __attribute__((address_space(1))) void*)g,
      (__attribute__((address_space(3))) void*)l, 16, 0, 0);
}

// ---------------- bf16 MFMA GEMM: C[M,N] = A[M,K] @ B[N,K]^T ----------------
// 128x128 tile, 4 waves (2x2), each wave 64x64, BK=64.
// B must have >= gridDim.x*128 rows (pad with zeros); store bounds-checked vs N.
template <typename TOUT>
__global__ __launch_bounds__(256) void gemm_mfma(const nbf16* __restrict__ A,
                                                 const nbf16* __restrict__ B,
                                                 TOUT* __restrict__ C,
                                                 int M, int N, int K) {
  __shared__ __align__(16) nbf16 Alds[128 * 64];
  __shared__ __align__(16) nbf16 Blds[128 * 64];
  int tid = threadIdx.x;
  int lane = tid & 63;
  int w = tid >> 6, wm = w >> 1, wn = w & 1;
  int bm = blockIdx.y * 128, bn = blockIdx.x * 128;
  f32x4 acc[4][4] = {};
  const nbf16* Ag = A + (size_t)bm * K;
  const nbf16* Bg = B + (size_t)bn * K;
  for (int k0 = 0; k0 < K; k0 += 64) {
#pragma unroll
    for (int q = 0; q < 4; ++q) {
      int e = (q * 256 + tid) * 8;
      int row = e >> 6, col = e & 63;
      gload_lds16(Ag + (size_t)row * K + k0 + col, &Alds[e]);
      gload_lds16(Bg + (size_t)row * K + k0 + col, &Blds[e]);
    }
    __syncthreads();
#pragma unroll
    for (int kk = 0; kk < 64; kk += 32) {
      bf16x8 af[4], bfr[4];
#pragma unroll
      for (int i = 0; i < 4; ++i) {
        af[i]  = *(const bf16x8*)&Alds[(wm * 64 + i * 16 + (lane & 15)) * 64 + kk + (lane >> 4) * 8];
        bfr[i] = *(const bf16x8*)&Blds[(wn * 64 + i * 16 + (lane & 15)) * 64 + kk + (lane >> 4) * 8];
      }
#pragma unroll
      for (int mi = 0; mi < 4; ++mi)
#pragma unroll
        for (int ni = 0; ni < 4; ++ni)
          acc[mi][ni] = __builtin_amdgcn_mfma_f32_16x16x32_bf16(af[mi], bfr[ni], acc[mi][ni], 0, 0, 0);
    }
    __syncthreads();
  }
#pragma unroll
  for (int mi = 0; mi < 4; ++mi)
#pragma unroll
    for (int ni = 0; ni < 4; ++ni) {
      int colw = bn + wn * 64 + ni * 16 + (lane & 15);
      if (colw >= N) continue;
#pragma unroll
      for (int j = 0; j < 4; ++j) {
        int roww = bm + wm * 64 + mi * 16 + (lane >> 4) * 4 + j;
        store_val(&C[(size_t)roww * N + colw], acc[mi][ni][j]);
      }
    }
}

// ---------------- f32 -> bf16 casts ----------------
__global__ __launch_bounds__(256) void cast_bf16(const float* __restrict__ in,
                                                 nbf16* __restrict__ out, long n) {
  long i = ((long)blockIdx.x * 256 + threadIdx.x) * 4;
  if (i >= n) return;
  float4 v = *(const float4*)(in + i);
  out[i] = (nbf16)v.x; out[i + 1] = (nbf16)v.y;
  out[i + 2] = (nbf16)v.z; out[i + 3] = (nbf16)v.w;
}

// in: [3088][1024] f32 -> out: [3200][1024] bf16 (rows >= 3088 zeroed)
__global__ __launch_bounds__(256) void cast_pad_w(const float* __restrict__ in,
                                                  nbf16* __restrict__ out) {
  long i = ((long)blockIdx.x * 256 + threadIdx.x) * 4;
  if (i >= (long)3200 * 1024) return;
  int row = (int)(i >> 10);
  if (row < DPROJ) {
    float4 v = *(const float4*)(in + i);
    out[i] = (nbf16)v.x; out[i + 1] = (nbf16)v.y;
    out[i + 2] = (nbf16)v.z; out[i + 3] = (nbf16)v.w;
  } else {
    out[i] = (nbf16)0.f; out[i + 1] = (nbf16)0.f;
    out[i + 2] = (nbf16)0.f; out[i + 3] = (nbf16)0.f;
  }
}

// ---------------- intra-chunk SSD with fused depthwise conv ----------------
// grid: bid = b*1024 + c*16 + h (2048 blocks), 256 threads
__global__ __launch_bounds__(256) void ssd_intra(
    const bf16* __restrict__ xw, const float* __restrict__ cw,
    const float* __restrict__ cb, const float* __restrict__ wbase,
    float* __restrict__ Ybuf, float* __restrict__ states,
    float* __restrict__ norm_diag, float* __restrict__ sdo_g,
    float* __restrict__ ndecay, float* __restrict__ Alast) {
  __shared__ float Cs[68][64];
  __shared__ float Bs[68][65];
  __shared__ float Xs[68][64];
  __shared__ float av[64], cums[64], mincs[64], dec[64], sdo_s[64];
  __shared__ float s_nd;
  float (*Sc)[64] = Cs;

  int tid = threadIdx.x;
  int h = blockIdx.x & 15;
  int c = (blockIdx.x >> 4) & 63;
  int b = blockIdx.x >> 10;

  for (int i = tid; i < 67 * 64; i += 256) {
    int row = i >> 6, n = i & 63;
    int t = c * 64 - 3 + row;
    float vc = 0.f, vb = 0.f, vx = 0.f;
    if (t >= 0) {
      const bf16* r = xw + ((size_t)(b * SEQL + t)) * DPROJ + h * 64 + n;
      vc = __bfloat162float(r[0]);
      vb = __bfloat162float(r[1024]);
      vx = __bfloat162float(r[2048]);
    }
    Cs[row][n] = vc; Bs[row][n] = vb; Xs[row][n] = vx;
  }
  if (tid < 64)
    av[tid] = __bfloat162float(xw[((size_t)(b * SEQL + c * 64 + tid)) * DPROJ + CDIM + h]) * wbase[h];
  __syncthreads();

  float rc[16], rb[16], rx[16];
  {
    int n = tid & 63;
    const float* wcc = cw + (size_t)(h * 64 + n) * 4;
    const float* wcb = cw + (size_t)(1024 + h * 64 + n) * 4;
    const float* wcx = cw + (size_t)(2048 + h * 64 + n) * 4;
    float bc = cb[h * 64 + n], bb = cb[1024 + h * 64 + n], bx = cb[2048 + h * 64 + n];
#pragma unroll
    for (int q = 0; q < 16; ++q) {
      int l = (tid >> 6) + q * 4;
      rc[q] = fmaf(Cs[l + 3][n], wcc[3], fmaf(Cs[l + 2][n], wcc[2],
               fmaf(Cs[l + 1][n], wcc[1], fmaf(Cs[l][n], wcc[0], bc))));
      rb[q] = fmaf(Bs[l + 3][n], wcb[3], fmaf(Bs[l + 2][n], wcb[2],
               fmaf(Bs[l + 1][n], wcb[1], fmaf(Bs[l][n], wcb[0], bb))));
      rx[q] = fmaf(Xs[l + 3][n], wcx[3], fmaf(Xs[l + 2][n], wcx[2],
               fmaf(Xs[l + 1][n], wcx[1], fmaf(Xs[l][n], wcx[0], bx))));
    }
  }
  __syncthreads();
  {
    int n = tid & 63;
#pragma unroll
    for (int q = 0; q < 16; ++q) {
      int l = (tid >> 6) + q * 4;
      Cs[l][n] = rc[q]; Bs[l][n] = rb[q]; Xs[l][n] = rx[q];
    }
  }
  __syncthreads();

  if (tid == 0) {
    float cum = 0.f, mn = 1e30f, mx = -1e30f;
    for (int l = 0; l < 64; ++l) {
      cum += av[l];
      cums[l] = cum;
      mn = fminf(mn, cum);
      mincs[l] = mn;
      mx = fmaxf(mx, cum);
    }
    float nd = 0.f;
    for (int l = 0; l < 64; ++l) {
      dec[l] = expf(mn - cums[l]);
      nd += dec[l];
      sdo_s[l] = expf(cums[l] - mx);
    }
    s_nd = nd;
  }
  __syncthreads();

  float sv[16];
#pragma unroll
  for (int k = 0; k < 16; ++k) {
    int i = tid + (k << 8);
    int l = i >> 6, s = i & 63;
    float v = 0.f;
    if (s <= l) {
      float g = 0.f;
#pragma unroll 8
      for (int n = 0; n < 64; ++n) g = fmaf(Cs[l][n], Bs[s][n], g);
      v = g * expf(mincs[l] - cums[s]);
    }
    sv[k] = v;
  }
  __syncthreads();
#pragma unroll
  for (int k = 0; k < 16; ++k) {
    int i = tid + (k << 8);
    Sc[i >> 6][i & 63] = sv[k];
  }
  __syncthreads();

  if (tid < 64) {
    int l = tid;
    float ndg = 0.f;
    for (int s = 0; s <= l; ++s) ndg += expf(mincs[l] - cums[s]);
    norm_diag[(size_t)blockIdx.x * 64 + l] = ndg;
    sdo_g[(size_t)blockIdx.x * 64 + l] = sdo_s[l];
  }
  if (tid == 0) {
    ndecay[blockIdx.x] = s_nd;
    Alast[((size_t)(b * NH + h)) * 64 + c] = cums[63];
  }

  size_t ybase = ((size_t)(b * SEQL + c * 64)) * DMODEL + h * 64;
  for (int i = tid; i < 4096; i += 256) {
    int l = i >> 6, p = i & 63;
    float y = 0.f;
    for (int s = 0; s <= l; ++s) y = fmaf(Sc[l][s], Xs[s][p], y);
    Ybuf[ybase + (size_t)l * DMODEL + p] = y;
  }
  size_t sbase = (size_t)blockIdx.x * 4096;
  for (int i = tid; i < 4096; i += 256) {
    int p = i >> 6, n = i & 63;
    float st = 0.f;
#pragma unroll 8
    for (int l = 0; l < 64; ++l) st = fmaf(dec[l] * Xs[l][p], Bs[l][n], st);
    states[sbase + i] = st;
  }
}

// ---------------- inter-chunk scan (in place: new[z] -> slot z-1) ----------------
// grid: bid = b*256 + h*16 + pg (512 blocks), 256 threads; each thread 1 element
__global__ __launch_bounds__(256) void ssd_scan(
    const float* __restrict__ Alast, float* __restrict__ states,
    const float* __restrict__ ndecay, float* __restrict__ nd_in) {
  __shared__ float cA[64], cB[64];
  int tid = threadIdx.x;
  int pg = blockIdx.x & 15, h = (blockIdx.x >> 4) & 15, b = blockIdx.x >> 8;
  if (tid == 0) {
    float cum = 0.f, minc = 0.f, ndR = 0.f;
    if (pg == 0) nd_in[(b * 64 + 0) * 16 + h] = 0.f;
    for (int z = 1; z < 64; ++z) {
      cum += Alast[(b * NH + h) * 64 + (z - 1)];
      float nm = fminf(minc, cum);
      cA[z] = expf(nm - minc);
      cB[z] = expf(nm - cum);
      minc = nm;
      ndR = cA[z] * ndR + cB[z] * ndecay[(b * 64 + (z - 1)) * 16 + h];
      if (pg == 0) nd_in[(b * 64 + z) * 16 + h] = ndR;
    }
  }
  __syncthreads();
  int off = pg * 256 + tid;
  float R = 0.f;
  for (int z = 1; z < 64; ++z) {
    size_t slot = ((size_t)(b * 64 + (z - 1)) * 16 + h) * 4096 + off;
    R = cA[z] * R + cB[z] * states[slot];
    states[slot] = R;
  }
}

// ---------------- off-diagonal + combine (conv fused for C); bf16 Y out ----------------
__global__ __launch_bounds__(256) void ssd_off(
    const bf16* __restrict__ xw, const float* __restrict__ cw,
    const float* __restrict__ cb, const float* __restrict__ states,
    const float* __restrict__ norm_diag, const float* __restrict__ sdo_g,
    const float* __restrict__ nd_in, const float* __restrict__ Ybuf,
    bf16* __restrict__ Ybf) {
  __shared__ float Cs[68][64];
  __shared__ float Ss[64][65];
  int tid = threadIdx.x;
  int h = blockIdx.x & 15;
  int c = (blockIdx.x >> 4) & 63;
  int b = blockIdx.x >> 10;

  for (int i = tid; i < 67 * 64; i += 256) {
    int row = i >> 6, n = i & 63;
    int t = c * 64 - 3 + row;
    Cs[row][n] = (t >= 0)
        ? __bfloat162float(xw[((size_t)(b * SEQL + t)) * DPROJ + h * 64 + n])
        : 0.f;
  }
  if (c > 0) {
    size_t sbase = (((size_t)(b * 64 + (c - 1)) * 16 + h)) * 4096;
    for (int i = tid; i < 4096; i += 256) Ss[i >> 6][i & 63] = states[sbase + i];
  } else {
    for (int i = tid; i < 4096; i += 256) Ss[i >> 6][i & 63] = 0.f;
  }
  __syncthreads();

  float rc[16];
  {
    int n = tid & 63;
    const float* wcc = cw + (size_t)(h * 64 + n) * 4;
    float bc = cb[h * 64 + n];
#pragma unroll
    for (int q = 0; q < 16; ++q) {
      int l = (tid >> 6) + q * 4;
      rc[q] = fmaf(Cs[l + 3][n], wcc[3], fmaf(Cs[l + 2][n], wcc[2],
               fmaf(Cs[l + 1][n], wcc[1], fmaf(Cs[l][n], wcc[0], bc))));
    }
  }
  __syncthreads();
  {
    int n = tid & 63;
#pragma unroll
    for (int q = 0; q < 16; ++q) Cs[(tid >> 6) + q * 4][n] = rc[q];
  }
  __syncthreads();

  float ndin = nd_in[blockIdx.x];
  size_t ybase = ((size_t)(b * SEQL + c * 64)) * DMODEL + h * 64;
  for (int i = tid; i < 4096; i += 256) {
    int l = i >> 6, p = i & 63;
    float yo = 0.f;
#pragma unroll 8
    for (int n = 0; n < 64; ++n) yo = fmaf(Cs[l][n], Ss[p][n], yo);
    float sd = sdo_g[(size_t)blockIdx.x * 64 + l];
    float nrm = norm_diag[(size_t)blockIdx.x * 64 + l] + ndin * sd;
    size_t yi = ybase + (size_t)l * DMODEL + p;
    Ybf[yi] = __float2bfloat16((Ybuf[yi] + yo * sd) / nrm);
  }
}

extern "C" void kernel_launch(void* const* d_in, const int* in_sizes, int n_in,
                              void* d_out, int out_size, void* d_ws, size_t ws_size,
                              hipStream_t stream) {
  const float* x          = (const float*)d_in[0];
  const float* in_proj_w  = (const float*)d_in[1];
  const float* conv_w     = (const float*)d_in[2];
  const float* conv_b     = (const float*)d_in[3];
  const float* w_base     = (const float*)d_in[4];
  const float* out_proj_w = (const float*)d_in[5];
  float* out = (float*)d_out;

  char* ws = (char*)d_ws;
  size_t off = 0;
  auto alloc = [&](size_t bytes) {
    void* p = ws + off;
    off += (bytes + 255) & ~(size_t)255;
    return p;
  };
  const size_t BT = (size_t)2 * SEQL;                        // 8192
  bf16* xIOw  = (bf16*)alloc(BT * DPROJ * 2);                // 50.6 MB
  float* Ybuf = (float*)alloc(BT * DMODEL * 4);              // 33.6 MB
  nbf16* xbf  = (nbf16*)alloc(BT * DMODEL * 2);              // 16.8 MB (later reused as Ybf)
  nbf16* wibf = (nbf16*)alloc((size_t)3200 * 1024 * 2);      // 6.6 MB
  nbf16* wobf = (nbf16*)alloc((size_t)1024 * 1024 * 2);      // 2.1 MB
  float* norm_diag = (float*)alloc((size_t)2048 * 64 * 4);
  float* sdo   = (float*)alloc((size_t)2048 * 64 * 4);
  float* ndec  = (float*)alloc((size_t)2048 * 4);
  float* Alast = (float*)alloc((size_t)2048 * 4);
  float* nd_in = (float*)alloc((size_t)2048 * 4);
  // total ~110.6 MB
  bf16* Ybf = (bf16*)xbf;       // xbf dead after in-proj GEMM
  float* states = out;          // dead before final GEMM overwrites d_out

  // 0) casts
  cast_bf16<<<(int)(BT * DMODEL / 4 / 256), 256, 0, stream>>>(x, xbf, BT * DMODEL);
  cast_pad_w<<<3200 * 1024 / 4 / 256, 256, 0, stream>>>(in_proj_w, wibf);
  cast_bf16<<<DMODEL * DMODEL / 4 / 256, 256, 0, stream>>>(out_proj_w, wobf, (long)DMODEL * DMODEL);
  // 1) in-projection GEMM (bf16 MFMA, bf16 out)
  gemm_mfma<bf16><<<dim3(25, BT / 128), 256, 0, stream>>>(
      xbf, wibf, xIOw, (int)BT, DPROJ, DMODEL);
  // 2) intra-chunk SSD (conv fused)
  ssd_intra<<<2048, 256, 0, stream>>>(xIOw, conv_w, conv_b, w_base,
                                      Ybuf, states, norm_diag, sdo, ndec, Alast);
  // 3) inter-chunk scan (in place on states)
  ssd_scan<<<512, 256, 0, stream>>>(Alast, states, ndec, nd_in);
  // 4) off-diagonal + normalize -> bf16 Y
  ssd_off<<<2048, 256, 0, stream>>>(xIOw, conv_w, conv_b, states,
                                    norm_diag, sdo, nd_in, Ybuf, Ybf);
  // 5) out-projection GEMM (bf16 MFMA, f32 out to d_out)
  gemm_mfma<float><<<dim3(DMODEL / 128, BT / 128), 256, 0, stream>>>(
      (const nbf16*)Ybf, wobf, out, (int)BT, DMODEL, DMODEL);
}

// Round 5
// 336.001 us; speedup vs baseline: 5.0646x; 1.6465x over previous
//
#include <hip/hip_runtime.h>
#include <hip/hip_bf16.h>
#include <math.h>
#include <stdint.h>

#define SEQL 4096
#define NH 16
#define CDIM 3072
#define DPROJ 3088
#define DMODEL 1024

typedef __hip_bfloat16 bf16;
typedef __bf16 nbf16;
typedef __attribute__((ext_vector_type(8))) __bf16 bf16x8;
typedef __attribute__((ext_vector_type(4))) float f32x4;

__device__ inline void store_val(float* p, float v) { *p = v; }
__device__ inline void store_val(nbf16* p, float v) { *p = (nbf16)v; }

__device__ __forceinline__ void gload_lds16(const void* g, void* l) {
  __builtin_amdgcn_global_load_lds(
      (const __attribute__((address_space(1))) void*)g,
      (__attribute__((address_space(3))) void*)l, 16, 0, 0);
}

// swizzled bf16 LDS index for [R][64] row-major tiles
__device__ __forceinline__ int swz(int row, int col) {
  return row * 64 + (col ^ ((row & 7) << 3));
}

// ---------------- bf16 MFMA GEMM: C[M,N] = A[M,K] @ B[N,K]^T ----------------
template <typename TOUT>
__global__ __launch_bounds__(256) void gemm_mfma(const nbf16* __restrict__ A,
                                                 const nbf16* __restrict__ B,
                                                 TOUT* __restrict__ C,
                                                 int M, int N, int K) {
  __shared__ __align__(16) nbf16 Alds[128 * 64];
  __shared__ __align__(16) nbf16 Blds[128 * 64];
  int tid = threadIdx.x;
  int lane = tid & 63;
  int w = tid >> 6, wm = w >> 1, wn = w & 1;
  int bm = blockIdx.y * 128, bn = blockIdx.x * 128;
  f32x4 acc[4][4] = {};
  const nbf16* Ag = A + (size_t)bm * K;
  const nbf16* Bg = B + (size_t)bn * K;
  for (int k0 = 0; k0 < K; k0 += 64) {
#pragma unroll
    for (int q = 0; q < 4; ++q) {
      int e = (q * 256 + tid) * 8;
      int row = e >> 6, col = e & 63;
      gload_lds16(Ag + (size_t)row * K + k0 + col, &Alds[e]);
      gload_lds16(Bg + (size_t)row * K + k0 + col, &Blds[e]);
    }
    __syncthreads();
#pragma unroll
    for (int kk = 0; kk < 64; kk += 32) {
      bf16x8 af[4], bfr[4];
#pragma unroll
      for (int i = 0; i < 4; ++i) {
        af[i]  = *(const bf16x8*)&Alds[(wm * 64 + i * 16 + (lane & 15)) * 64 + kk + (lane >> 4) * 8];
        bfr[i] = *(const bf16x8*)&Blds[(wn * 64 + i * 16 + (lane & 15)) * 64 + kk + (lane >> 4) * 8];
      }
#pragma unroll
      for (int mi = 0; mi < 4; ++mi)
#pragma unroll
        for (int ni = 0; ni < 4; ++ni)
          acc[mi][ni] = __builtin_amdgcn_mfma_f32_16x16x32_bf16(af[mi], bfr[ni], acc[mi][ni], 0, 0, 0);
    }
    __syncthreads();
  }
#pragma unroll
  for (int mi = 0; mi < 4; ++mi)
#pragma unroll
    for (int ni = 0; ni < 4; ++ni) {
      int colw = bn + wn * 64 + ni * 16 + (lane & 15);
      if (colw >= N) continue;
#pragma unroll
      for (int j = 0; j < 4; ++j) {
        int roww = bm + wm * 64 + mi * 16 + (lane >> 4) * 4 + j;
        store_val(&C[(size_t)roww * N + colw], acc[mi][ni][j]);
      }
    }
}

// ---------------- f32 -> bf16 casts ----------------
__global__ __launch_bounds__(256) void cast_bf16(const float* __restrict__ in,
                                                 nbf16* __restrict__ out, long n) {
  long i = ((long)blockIdx.x * 256 + threadIdx.x) * 4;
  if (i >= n) return;
  float4 v = *(const float4*)(in + i);
  out[i] = (nbf16)v.x; out[i + 1] = (nbf16)v.y;
  out[i + 2] = (nbf16)v.z; out[i + 3] = (nbf16)v.w;
}

__global__ __launch_bounds__(256) void cast_pad_w(const float* __restrict__ in,
                                                  nbf16* __restrict__ out) {
  long i = ((long)blockIdx.x * 256 + threadIdx.x) * 4;
  if (i >= (long)3200 * 1024) return;
  int row = (int)(i >> 10);
  if (row < DPROJ) {
    float4 v = *(const float4*)(in + i);
    out[i] = (nbf16)v.x; out[i + 1] = (nbf16)v.y;
    out[i + 2] = (nbf16)v.z; out[i + 3] = (nbf16)v.w;
  } else {
    out[i] = (nbf16)0.f; out[i + 1] = (nbf16)0.f;
    out[i + 2] = (nbf16)0.f; out[i + 3] = (nbf16)0.f;
  }
}

// ---------------- intra-chunk SSD: conv + scalars + 3 MFMA matmuls ----------------
// grid: bid = b*1024 + c*16 + h (2048 blocks), 256 threads (4 waves)
__global__ __launch_bounds__(256) void ssd_intra(
    const nbf16* __restrict__ xw, const float* __restrict__ cw,
    const float* __restrict__ cb, const float* __restrict__ wbase,
    float* __restrict__ Ybuf, float* __restrict__ states,
    float* __restrict__ norm_diag, float* __restrict__ sdo_g,
    float* __restrict__ ndecay, float* __restrict__ Alast) {
  __shared__ __align__(16) nbf16 Craw[68 * 64];   // raw, then conv'd C (rows 0..63)
  __shared__ __align__(16) nbf16 Braw[68 * 64];   // raw, then conv'd B
  __shared__ __align__(16) nbf16 Xraw[68 * 64];   // raw X; aliased as S later
  __shared__ __align__(16) nbf16 BbT[64 * 64];    // conv'd B transposed [n][l]
  __shared__ __align__(16) nbf16 XbT[64 * 64];    // conv'd X transposed [p][l]
  __shared__ float cums_s[64], mincs_s[64], dec_s[64];
  nbf16* Sb = Xraw;

  int tid = threadIdx.x;
  int lane = tid & 63;
  int w = tid >> 6;
  int h = blockIdx.x & 15;
  int c = (blockIdx.x >> 4) & 63;
  int b = blockIdx.x >> 10;

  // raw loads (swizzled row-major), rows t = c*64-3 .. c*64+63
  for (int i = tid; i < 67 * 64; i += 256) {
    int row = i >> 6, n = i & 63;
    int t = c * 64 - 3 + row;
    nbf16 vc = (nbf16)0.f, vb = vc, vx = vc;
    if (t >= 0) {
      const nbf16* r = xw + ((size_t)(b * SEQL + t)) * DPROJ + h * 64 + n;
      vc = r[0]; vb = r[1024]; vx = r[2048];
    }
    int idx = swz(row, n);
    Craw[idx] = vc; Braw[idx] = vb; Xraw[idx] = vx;
  }

  // wave 0: prefix scan chain (shfl-parallel)
  if (w == 0) {
    float a = (float)xw[((size_t)(b * SEQL + c * 64 + lane)) * DPROJ + CDIM + h] * wbase[h];
    float cum = a;
#pragma unroll
    for (int d = 1; d < 64; d <<= 1) {
      float t = __shfl_up(cum, d, 64);
      if (lane >= d) cum += t;
    }
    float mn = cum;
#pragma unroll
    for (int d = 1; d < 64; d <<= 1) {
      float t = __shfl_up(mn, d, 64);
      if (lane >= d) mn = fminf(mn, t);
    }
    float mnall = __shfl(mn, 63, 64);
    float mx = cum;
#pragma unroll
    for (int d = 1; d < 64; d <<= 1) mx = fmaxf(mx, __shfl_xor(mx, d, 64));
    float dec = expf(mnall - cum);
    float sdo = expf(cum - mx);
    float nd = dec;
#pragma unroll
    for (int d = 1; d < 64; d <<= 1) nd += __shfl_xor(nd, d, 64);
    cums_s[lane] = cum; mincs_s[lane] = mn; dec_s[lane] = dec;
    sdo_g[(size_t)blockIdx.x * 64 + lane] = sdo;
    if (lane == 0) ndecay[blockIdx.x] = nd;
    if (lane == 63) Alast[((size_t)(b * NH + h)) * 64 + c] = cum;
  }
  __syncthreads();

  // depthwise causal conv(4) into regs
  float rc[16], rb[16], rx[16];
  {
    int n = tid & 63, base = tid >> 6;
    const float* wcc = cw + (size_t)(h * 64 + n) * 4;
    const float* wcb = wcc + 4096;
    const float* wcx = wcc + 8192;
    float bcc = cb[h * 64 + n], bcb = cb[1024 + h * 64 + n], bcx = cb[2048 + h * 64 + n];
#pragma unroll
    for (int q = 0; q < 16; ++q) {
      int l = base + q * 4;
      float aC = bcc, aB = bcb, aX = bcx;
#pragma unroll
      for (int d = 0; d < 4; ++d) {
        int idx = swz(l + d, n);
        aC = fmaf((float)Craw[idx], wcc[d], aC);
        aB = fmaf((float)Braw[idx], wcb[d], aB);
        aX = fmaf((float)Xraw[idx], wcx[d], aX);
      }
      rc[q] = aC; rb[q] = aB; rx[q] = aX;
    }
  }
  __syncthreads();
  {
    int n = tid & 63, base = tid >> 6;
#pragma unroll
    for (int q = 0; q < 16; ++q) {
      int l = base + q * 4;
      Craw[swz(l, n)] = (nbf16)rc[q];
      Braw[swz(l, n)] = (nbf16)rb[q];
      BbT[swz(n, l)] = (nbf16)rb[q];
      XbT[swz(n, l)] = (nbf16)rx[q];
    }
  }
  __syncthreads();

  // ---- matmul 1: S[l][s] = (C_l . B_s) * exp(mincs[l]-cums[s]), s<=l ----
  {
    f32x4 accS[4] = {};
#pragma unroll
    for (int kk = 0; kk < 64; kk += 32) {
      int arow = w * 16 + (lane & 15);
      int c0 = kk + (lane >> 4) * 8;
      bf16x8 af = *(const bf16x8*)&Craw[swz(arow, c0)];
#pragma unroll
      for (int nb = 0; nb < 4; ++nb) {
        int brow = nb * 16 + (lane & 15);
        bf16x8 bfr = *(const bf16x8*)&Braw[swz(brow, c0)];
        accS[nb] = __builtin_amdgcn_mfma_f32_16x16x32_bf16(af, bfr, accS[nb], 0, 0, 0);
      }
    }
    float rowsum[4] = {0.f, 0.f, 0.f, 0.f};
#pragma unroll
    for (int nb = 0; nb < 4; ++nb) {
      int s = nb * 16 + (lane & 15);
      float cs = cums_s[s];
#pragma unroll
      for (int r = 0; r < 4; ++r) {
        int l = w * 16 + (lane >> 4) * 4 + r;
        float e = (s <= l) ? expf(mincs_s[l] - cs) : 0.f;
        rowsum[r] += e;
        Sb[swz(l, s)] = (nbf16)(accS[nb][r] * e);
      }
    }
#pragma unroll
    for (int r = 0; r < 4; ++r) {
#pragma unroll
      for (int d = 1; d < 16; d <<= 1) rowsum[r] += __shfl_xor(rowsum[r], d, 64);
      if ((lane & 15) == 0) {
        int l = w * 16 + (lane >> 4) * 4 + r;
        norm_diag[(size_t)blockIdx.x * 64 + l] = rowsum[r];
      }
    }
  }
  __syncthreads();

  // ---- matmul 2: Y_diag[l][p] = sum_s S[l][s] * X[s][p] ----
  {
    f32x4 accY[4] = {};
#pragma unroll
    for (int kk = 0; kk < 64; kk += 32) {
      int arow = w * 16 + (lane & 15);
      int c0 = kk + (lane >> 4) * 8;
      bf16x8 af = *(const bf16x8*)&Sb[swz(arow, c0)];
#pragma unroll
      for (int pb = 0; pb < 4; ++pb) {
        int prow = pb * 16 + (lane & 15);
        bf16x8 bfr = *(const bf16x8*)&XbT[swz(prow, c0)];
        accY[pb] = __builtin_amdgcn_mfma_f32_16x16x32_bf16(af, bfr, accY[pb], 0, 0, 0);
      }
    }
    size_t ybase = ((size_t)(b * SEQL + c * 64)) * DMODEL + h * 64;
#pragma unroll
    for (int pb = 0; pb < 4; ++pb) {
      int p = pb * 16 + (lane & 15);
#pragma unroll
      for (int r = 0; r < 4; ++r) {
        int l = w * 16 + (lane >> 4) * 4 + r;
        Ybuf[ybase + (size_t)l * DMODEL + p] = accY[pb][r];
      }
    }
  }

  // ---- matmul 3: states[p][n] = sum_l dec[l]*X[l][p]*B[l][n] ----
  {
    f32x4 accT[4] = {};
#pragma unroll
    for (int kk = 0; kk < 64; kk += 32) {
      int prow = w * 16 + (lane & 15);
      int c0 = kk + (lane >> 4) * 8;
      bf16x8 xf = *(const bf16x8*)&XbT[swz(prow, c0)];
      bf16x8 af;
#pragma unroll
      for (int j = 0; j < 8; ++j) af[j] = (nbf16)((float)xf[j] * dec_s[c0 + j]);
#pragma unroll
      for (int nb = 0; nb < 4; ++nb) {
        int nrow = nb * 16 + (lane & 15);
        bf16x8 bfr = *(const bf16x8*)&BbT[swz(nrow, c0)];
        accT[nb] = __builtin_amdgcn_mfma_f32_16x16x32_bf16(af, bfr, accT[nb], 0, 0, 0);
      }
    }
    size_t sbase = (size_t)blockIdx.x * 4096;
#pragma unroll
    for (int nb = 0; nb < 4; ++nb) {
      int n = nb * 16 + (lane & 15);
#pragma unroll
      for (int r = 0; r < 4; ++r) {
        int p = w * 16 + (lane >> 4) * 4 + r;
        states[sbase + p * 64 + n] = accT[nb][r];
      }
    }
  }
}

// ---------------- inter-chunk scan (in place: new[z] -> slot z-1) ----------------
__global__ __launch_bounds__(256) void ssd_scan(
    const float* __restrict__ Alast, float* __restrict__ states,
    const float* __restrict__ ndecay, float* __restrict__ nd_in) {
  __shared__ float cA[64], cB[64];
  int tid = threadIdx.x;
  int pg = blockIdx.x & 15, h = (blockIdx.x >> 4) & 15, b = blockIdx.x >> 8;
  if (tid == 0) {
    float cum = 0.f, minc = 0.f, ndR = 0.f;
    if (pg == 0) nd_in[(b * 64 + 0) * 16 + h] = 0.f;
    for (int z = 1; z < 64; ++z) {
      cum += Alast[(b * NH + h) * 64 + (z - 1)];
      float nm = fminf(minc, cum);
      cA[z] = expf(nm - minc);
      cB[z] = expf(nm - cum);
      minc = nm;
      ndR = cA[z] * ndR + cB[z] * ndecay[(b * 64 + (z - 1)) * 16 + h];
      if (pg == 0) nd_in[(b * 64 + z) * 16 + h] = ndR;
    }
  }
  __syncthreads();
  int off = pg * 256 + tid;
  float R = 0.f;
  for (int z = 1; z < 64; ++z) {
    size_t slot = ((size_t)(b * 64 + (z - 1)) * 16 + h) * 4096 + off;
    R = cA[z] * R + cB[z] * states[slot];
    states[slot] = R;
  }
}

// ---------------- off-diagonal + combine (MFMA) ----------------
__global__ __launch_bounds__(256) void ssd_off(
    const nbf16* __restrict__ xw, const float* __restrict__ cw,
    const float* __restrict__ cb, const float* __restrict__ states,
    const float* __restrict__ norm_diag, const float* __restrict__ sdo_g,
    const float* __restrict__ nd_in, const float* __restrict__ Ybuf,
    nbf16* __restrict__ Ybf) {
  __shared__ __align__(16) nbf16 Craw[68 * 64];
  __shared__ __align__(16) nbf16 Ssb[64 * 64];
  int tid = threadIdx.x, lane = tid & 63, w = tid >> 6;
  int h = blockIdx.x & 15, c = (blockIdx.x >> 4) & 63, b = blockIdx.x >> 10;

  for (int i = tid; i < 67 * 64; i += 256) {
    int row = i >> 6, n = i & 63;
    int t = c * 64 - 3 + row;
    nbf16 v = (nbf16)0.f;
    if (t >= 0) v = xw[((size_t)(b * SEQL + t)) * DPROJ + h * 64 + n];
    Craw[swz(row, n)] = v;
  }
  if (c > 0) {
    size_t sbase = (((size_t)(b * 64 + (c - 1)) * 16 + h)) * 4096;
    for (int i = tid; i < 4096; i += 256) {
      int p = i >> 6, n = i & 63;
      Ssb[swz(p, n)] = (nbf16)states[sbase + i];
    }
  } else {
    for (int i = tid; i < 4096; i += 256) Ssb[i] = (nbf16)0.f;
  }
  __syncthreads();

  float rc[16];
  {
    int n = tid & 63, base = tid >> 6;
    const float* wcc = cw + (size_t)(h * 64 + n) * 4;
    float bcc = cb[h * 64 + n];
#pragma unroll
    for (int q = 0; q < 16; ++q) {
      int l = base + q * 4;
      float aC = bcc;
#pragma unroll
      for (int d = 0; d < 4; ++d) aC = fmaf((float)Craw[swz(l + d, n)], wcc[d], aC);
      rc[q] = aC;
    }
  }
  __syncthreads();
  {
    int n = tid & 63, base = tid >> 6;
#pragma unroll
    for (int q = 0; q < 16; ++q) Craw[swz(base + q * 4, n)] = (nbf16)rc[q];
  }
  __syncthreads();

  // Y_off[l][p] = sum_n C[l][n] * Ss[p][n]
  f32x4 accO[4] = {};
#pragma unroll
  for (int kk = 0; kk < 64; kk += 32) {
    int arow = w * 16 + (lane & 15);
    int c0 = kk + (lane >> 4) * 8;
    bf16x8 af = *(const bf16x8*)&Craw[swz(arow, c0)];
#pragma unroll
    for (int pb = 0; pb < 4; ++pb) {
      int prow = pb * 16 + (lane & 15);
      bf16x8 bfr = *(const bf16x8*)&Ssb[swz(prow, c0)];
      accO[pb] = __builtin_amdgcn_mfma_f32_16x16x32_bf16(af, bfr, accO[pb], 0, 0, 0);
    }
  }
  float ndin = nd_in[blockIdx.x];
  size_t ybase = ((size_t)(b * SEQL + c * 64)) * DMODEL + h * 64;
#pragma unroll
  for (int r = 0; r < 4; ++r) {
    int l = w * 16 + (lane >> 4) * 4 + r;
    float sd = sdo_g[(size_t)blockIdx.x * 64 + l];
    float nrm = norm_diag[(size_t)blockIdx.x * 64 + l] + ndin * sd;
#pragma unroll
    for (int pb = 0; pb < 4; ++pb) {
      int p = pb * 16 + (lane & 15);
      size_t yi = ybase + (size_t)l * DMODEL + p;
      Ybf[yi] = (nbf16)((Ybuf[yi] + accO[pb][r] * sd) / nrm);
    }
  }
}

extern "C" void kernel_launch(void* const* d_in, const int* in_sizes, int n_in,
                              void* d_out, int out_size, void* d_ws, size_t ws_size,
                              hipStream_t stream) {
  const float* x          = (const float*)d_in[0];
  const float* in_proj_w  = (const float*)d_in[1];
  const float* conv_w     = (const float*)d_in[2];
  const float* conv_b     = (const float*)d_in[3];
  const float* w_base     = (const float*)d_in[4];
  const float* out_proj_w = (const float*)d_in[5];
  float* out = (float*)d_out;

  char* ws = (char*)d_ws;
  size_t off = 0;
  auto alloc = [&](size_t bytes) {
    void* p = ws + off;
    off += (bytes + 255) & ~(size_t)255;
    return p;
  };
  const size_t BT = (size_t)2 * SEQL;                        // 8192
  nbf16* xIOw = (nbf16*)alloc(BT * DPROJ * 2);               // 50.6 MB
  float* Ybuf = (float*)alloc(BT * DMODEL * 4);              // 33.6 MB
  nbf16* xbf  = (nbf16*)alloc(BT * DMODEL * 2);              // 16.8 MB (reused as Ybf)
  nbf16* wibf = (nbf16*)alloc((size_t)3200 * 1024 * 2);      // 6.6 MB
  nbf16* wobf = (nbf16*)alloc((size_t)1024 * 1024 * 2);      // 2.1 MB
  float* norm_diag = (float*)alloc((size_t)2048 * 64 * 4);
  float* sdo   = (float*)alloc((size_t)2048 * 64 * 4);
  float* ndec  = (float*)alloc((size_t)2048 * 4);
  float* Alast = (float*)alloc((size_t)2048 * 4);
  float* nd_in = (float*)alloc((size_t)2048 * 4);
  nbf16* Ybf = xbf;             // xbf dead after in-proj GEMM
  float* states = out;          // dead before final GEMM overwrites d_out

  cast_bf16<<<(int)(BT * DMODEL / 4 / 256), 256, 0, stream>>>(x, xbf, BT * DMODEL);
  cast_pad_w<<<3200 * 1024 / 4 / 256, 256, 0, stream>>>(in_proj_w, wibf);
  cast_bf16<<<DMODEL * DMODEL / 4 / 256, 256, 0, stream>>>(out_proj_w, wobf, (long)DMODEL * DMODEL);
  gemm_mfma<nbf16><<<dim3(25, BT / 128), 256, 0, stream>>>(
      xbf, wibf, xIOw, (int)BT, DPROJ, DMODEL);
  ssd_intra<<<2048, 256, 0, stream>>>(xIOw, conv_w, conv_b, w_base,
                                      Ybuf, states, norm_diag, sdo, ndec, Alast);
  ssd_scan<<<512, 256, 0, stream>>>(Alast, states, ndec, nd_in);
  ssd_off<<<2048, 256, 0, stream>>>(xIOw, conv_w, conv_b, states,
                                    norm_diag, sdo, nd_in, Ybuf, Ybf);
  gemm_mfma<float><<<dim3(DMODEL / 128, BT / 128), 256, 0, stream>>>(
      Ybf, wobf, out, (int)BT, DMODEL, DMODEL);
}

// Round 6
// 301.874 us; speedup vs baseline: 5.6372x; 1.1131x over previous
//
#include <hip/hip_runtime.h>
#include <hip/hip_bf16.h>
#include <math.h>
#include <stdint.h>

#define SEQL 4096
#define NH 16
#define CDIM 3072
#define DPROJ 3088
#define DMODEL 1024

typedef __bf16 nbf16;
typedef __attribute__((ext_vector_type(8))) __bf16 bf16x8;
typedef __attribute__((ext_vector_type(4))) float f32x4;

__device__ inline void store_val(float* p, float v) { *p = v; }
__device__ inline void store_val(nbf16* p, float v) { *p = (nbf16)v; }

__device__ __forceinline__ void gload_lds16(const void* g, void* l) {
  __builtin_amdgcn_global_load_lds(
      (const __attribute__((address_space(1))) void*)g,
      (__attribute__((address_space(3))) void*)l, 16, 0, 0);
}

// swizzled bf16 LDS index for [R][64] row-major tiles
__device__ __forceinline__ int swz(int row, int col) {
  return row * 64 + (col ^ ((row & 7) << 3));
}

// ---------------- bf16 MFMA GEMM: C[M,N] = A[M,K] @ B[N,K]^T ----------------
// 256x128 tile, 8 waves (4M x 2N), each wave 64x64, BK=64. XCD-swizzled grid.
// Requires (gridDim.x*gridDim.y) % 8 == 0, M % 256 == 0, B padded to gridDim.x*128 rows.
template <typename TOUT>
__global__ __launch_bounds__(512) void gemm_mfma(const nbf16* __restrict__ A,
                                                 const nbf16* __restrict__ B,
                                                 TOUT* __restrict__ C,
                                                 int M, int N, int K) {
  __shared__ __align__(16) nbf16 Alds[256 * 64];
  __shared__ __align__(16) nbf16 Blds[128 * 64];
  int tid = threadIdx.x;
  int lane = tid & 63;
  int w = tid >> 6, wm = w >> 1, wn = w & 1;   // wm 0..3, wn 0..1
  // T1: bijective XCD swizzle (nwg % 8 == 0)
  int gx = gridDim.x;
  int nwg = gx * gridDim.y;
  int orig = blockIdx.y * gx + blockIdx.x;
  int wg = (orig & 7) * (nwg >> 3) + (orig >> 3);
  int bm = (wg / gx) * 256, bn = (wg % gx) * 128;
  f32x4 acc[4][4] = {};
  const nbf16* Ag = A + (size_t)bm * K;
  const nbf16* Bg = B + (size_t)bn * K;
  for (int k0 = 0; k0 < K; k0 += 64) {
#pragma unroll
    for (int q = 0; q < 4; ++q) {
      int e = (q * 512 + tid) * 8;
      int row = e >> 6, col = e & 63;
      gload_lds16(Ag + (size_t)row * K + k0 + col, &Alds[e]);
    }
#pragma unroll
    for (int q = 0; q < 2; ++q) {
      int e = (q * 512 + tid) * 8;
      int row = e >> 6, col = e & 63;
      gload_lds16(Bg + (size_t)row * K + k0 + col, &Blds[e]);
    }
    __syncthreads();
#pragma unroll
    for (int kk = 0; kk < 64; kk += 32) {
      bf16x8 af[4], bfr[4];
#pragma unroll
      for (int i = 0; i < 4; ++i) {
        af[i]  = *(const bf16x8*)&Alds[(wm * 64 + i * 16 + (lane & 15)) * 64 + kk + (lane >> 4) * 8];
        bfr[i] = *(const bf16x8*)&Blds[(wn * 64 + i * 16 + (lane & 15)) * 64 + kk + (lane >> 4) * 8];
      }
#pragma unroll
      for (int mi = 0; mi < 4; ++mi)
#pragma unroll
        for (int ni = 0; ni < 4; ++ni)
          acc[mi][ni] = __builtin_amdgcn_mfma_f32_16x16x32_bf16(af[mi], bfr[ni], acc[mi][ni], 0, 0, 0);
    }
    __syncthreads();
  }
#pragma unroll
  for (int mi = 0; mi < 4; ++mi)
#pragma unroll
    for (int ni = 0; ni < 4; ++ni) {
      int colw = bn + wn * 64 + ni * 16 + (lane & 15);
      if (colw >= N) continue;
#pragma unroll
      for (int j = 0; j < 4; ++j) {
        int roww = bm + wm * 64 + mi * 16 + (lane >> 4) * 4 + j;
        store_val(&C[(size_t)roww * N + colw], acc[mi][ni][j]);
      }
    }
}

// ---------------- f32 -> bf16 casts ----------------
__global__ __launch_bounds__(256) void cast_bf16(const float* __restrict__ in,
                                                 nbf16* __restrict__ out, long n) {
  long i = ((long)blockIdx.x * 256 + threadIdx.x) * 4;
  if (i >= n) return;
  float4 v = *(const float4*)(in + i);
  out[i] = (nbf16)v.x; out[i + 1] = (nbf16)v.y;
  out[i + 2] = (nbf16)v.z; out[i + 3] = (nbf16)v.w;
}

__global__ __launch_bounds__(256) void cast_pad_w(const float* __restrict__ in,
                                                  nbf16* __restrict__ out) {
  long i = ((long)blockIdx.x * 256 + threadIdx.x) * 4;
  if (i >= (long)3200 * 1024) return;
  int row = (int)(i >> 10);
  if (row < DPROJ) {
    float4 v = *(const float4*)(in + i);
    out[i] = (nbf16)v.x; out[i + 1] = (nbf16)v.y;
    out[i + 2] = (nbf16)v.z; out[i + 3] = (nbf16)v.w;
  } else {
    out[i] = (nbf16)0.f; out[i + 1] = (nbf16)0.f;
    out[i + 2] = (nbf16)0.f; out[i + 3] = (nbf16)0.f;
  }
}

// ---------------- intra-chunk SSD: conv + scalars + 3 MFMA matmuls ----------------
// grid: bid = b*1024 + c*16 + h (2048 blocks), 256 threads (4 waves)
__global__ __launch_bounds__(256) void ssd_intra(
    const nbf16* __restrict__ xw, const float* __restrict__ cw,
    const float* __restrict__ cb, const float* __restrict__ wbase,
    nbf16* __restrict__ Ydg, nbf16* __restrict__ stG,
    float* __restrict__ norm_diag, float* __restrict__ sdo_g,
    float* __restrict__ ndecay, float* __restrict__ Alast) {
  __shared__ __align__(16) nbf16 Craw[68 * 64];
  __shared__ __align__(16) nbf16 Braw[68 * 64];
  __shared__ __align__(16) nbf16 Xraw[68 * 64];
  __shared__ __align__(16) nbf16 BbT[64 * 64];
  __shared__ __align__(16) nbf16 XbT[64 * 64];
  __shared__ float cums_s[64], mincs_s[64], dec_s[64];
  nbf16* Sb = Xraw;

  int tid = threadIdx.x;
  int lane = tid & 63;
  int w = tid >> 6;
  int h = blockIdx.x & 15;
  int c = (blockIdx.x >> 4) & 63;
  int b = blockIdx.x >> 10;

  // vectorized raw loads: 67 rows x 8 octs per tensor
  for (int i = tid; i < 67 * 8; i += 256) {
    int row = i >> 3, n0 = (i & 7) * 8;
    int t = c * 64 - 3 + row;
    bf16x8 vc = {}, vb = {}, vx = {};
    if (t >= 0) {
      const nbf16* r = xw + ((size_t)(b * SEQL + t)) * DPROJ + h * 64 + n0;
      vc = *(const bf16x8*)(r);
      vb = *(const bf16x8*)(r + 1024);
      vx = *(const bf16x8*)(r + 2048);
    }
    int idx = swz(row, n0);
    *(bf16x8*)&Craw[idx] = vc;
    *(bf16x8*)&Braw[idx] = vb;
    *(bf16x8*)&Xraw[idx] = vx;
  }

  if (w == 0) {
    float a = (float)xw[((size_t)(b * SEQL + c * 64 + lane)) * DPROJ + CDIM + h] * wbase[h];
    float cum = a;
#pragma unroll
    for (int d = 1; d < 64; d <<= 1) {
      float t = __shfl_up(cum, d, 64);
      if (lane >= d) cum += t;
    }
    float mn = cum;
#pragma unroll
    for (int d = 1; d < 64; d <<= 1) {
      float t = __shfl_up(mn, d, 64);
      if (lane >= d) mn = fminf(mn, t);
    }
    float mnall = __shfl(mn, 63, 64);
    float mx = cum;
#pragma unroll
    for (int d = 1; d < 64; d <<= 1) mx = fmaxf(mx, __shfl_xor(mx, d, 64));
    float dec = expf(mnall - cum);
    float sdo = expf(cum - mx);
    float nd = dec;
#pragma unroll
    for (int d = 1; d < 64; d <<= 1) nd += __shfl_xor(nd, d, 64);
    cums_s[lane] = cum; mincs_s[lane] = mn; dec_s[lane] = dec;
    sdo_g[(size_t)blockIdx.x * 64 + lane] = sdo;
    if (lane == 0) ndecay[blockIdx.x] = nd;
    if (lane == 63) Alast[((size_t)(b * NH + h)) * 64 + c] = cum;
  }
  __syncthreads();

  // depthwise causal conv(4)
  float rc[16], rb[16], rx[16];
  {
    int n = tid & 63, base = tid >> 6;
    const float* wcc = cw + (size_t)(h * 64 + n) * 4;
    const float* wcb = wcc + 4096;
    const float* wcx = wcc + 8192;
    float bcc = cb[h * 64 + n], bcb = cb[1024 + h * 64 + n], bcx = cb[2048 + h * 64 + n];
#pragma unroll
    for (int q = 0; q < 16; ++q) {
      int l = base + q * 4;
      float aC = bcc, aB = bcb, aX = bcx;
#pragma unroll
      for (int d = 0; d < 4; ++d) {
        int idx = swz(l + d, n);
        aC = fmaf((float)Craw[idx], wcc[d], aC);
        aB = fmaf((float)Braw[idx], wcb[d], aB);
        aX = fmaf((float)Xraw[idx], wcx[d], aX);
      }
      rc[q] = aC; rb[q] = aB; rx[q] = aX;
    }
  }
  __syncthreads();
  {
    int n = tid & 63, base = tid >> 6;
#pragma unroll
    for (int q = 0; q < 16; ++q) {
      int l = base + q * 4;
      Craw[swz(l, n)] = (nbf16)rc[q];
      Braw[swz(l, n)] = (nbf16)rb[q];
      BbT[swz(n, l)] = (nbf16)rb[q];
      XbT[swz(n, l)] = (nbf16)rx[q];
    }
  }
  __syncthreads();

  // matmul 1: S[l][s] = (C_l . B_s) * exp(mincs[l]-cums[s]), s<=l
  {
    f32x4 accS[4] = {};
#pragma unroll
    for (int kk = 0; kk < 64; kk += 32) {
      int arow = w * 16 + (lane & 15);
      int c0 = kk + (lane >> 4) * 8;
      bf16x8 af = *(const bf16x8*)&Craw[swz(arow, c0)];
#pragma unroll
      for (int nb = 0; nb < 4; ++nb) {
        int brow = nb * 16 + (lane & 15);
        bf16x8 bfr = *(const bf16x8*)&Braw[swz(brow, c0)];
        accS[nb] = __builtin_amdgcn_mfma_f32_16x16x32_bf16(af, bfr, accS[nb], 0, 0, 0);
      }
    }
    float rowsum[4] = {0.f, 0.f, 0.f, 0.f};
#pragma unroll
    for (int nb = 0; nb < 4; ++nb) {
      int s = nb * 16 + (lane & 15);
      float cs = cums_s[s];
#pragma unroll
      for (int r = 0; r < 4; ++r) {
        int l = w * 16 + (lane >> 4) * 4 + r;
        float e = (s <= l) ? expf(mincs_s[l] - cs) : 0.f;
        rowsum[r] += e;
        Sb[swz(l, s)] = (nbf16)(accS[nb][r] * e);
      }
    }
#pragma unroll
    for (int r = 0; r < 4; ++r) {
#pragma unroll
      for (int d = 1; d < 16; d <<= 1) rowsum[r] += __shfl_xor(rowsum[r], d, 64);
      if ((lane & 15) == 0) {
        int l = w * 16 + (lane >> 4) * 4 + r;
        norm_diag[(size_t)blockIdx.x * 64 + l] = rowsum[r];
      }
    }
  }
  __syncthreads();

  // matmul 2: Y_diag[l][p] = sum_s S[l][s] * X[s][p]  (bf16 out)
  {
    f32x4 accY[4] = {};
#pragma unroll
    for (int kk = 0; kk < 64; kk += 32) {
      int arow = w * 16 + (lane & 15);
      int c0 = kk + (lane >> 4) * 8;
      bf16x8 af = *(const bf16x8*)&Sb[swz(arow, c0)];
#pragma unroll
      for (int pb = 0; pb < 4; ++pb) {
        int prow = pb * 16 + (lane & 15);
        bf16x8 bfr = *(const bf16x8*)&XbT[swz(prow, c0)];
        accY[pb] = __builtin_amdgcn_mfma_f32_16x16x32_bf16(af, bfr, accY[pb], 0, 0, 0);
      }
    }
    size_t ybase = ((size_t)(b * SEQL + c * 64)) * DMODEL + h * 64;
#pragma unroll
    for (int pb = 0; pb < 4; ++pb) {
      int p = pb * 16 + (lane & 15);
#pragma unroll
      for (int r = 0; r < 4; ++r) {
        int l = w * 16 + (lane >> 4) * 4 + r;
        Ydg[ybase + (size_t)l * DMODEL + p] = (nbf16)accY[pb][r];
      }
    }
  }

  // matmul 3: states[p][n] = sum_l dec[l]*X[l][p]*B[l][n]  (bf16 out, [b,h,c,p*64+n])
  {
    f32x4 accT[4] = {};
#pragma unroll
    for (int kk = 0; kk < 64; kk += 32) {
      int prow = w * 16 + (lane & 15);
      int c0 = kk + (lane >> 4) * 8;
      bf16x8 xf = *(const bf16x8*)&XbT[swz(prow, c0)];
      bf16x8 af;
#pragma unroll
      for (int j = 0; j < 8; ++j) af[j] = (nbf16)((float)xf[j] * dec_s[c0 + j]);
#pragma unroll
      for (int nb = 0; nb < 4; ++nb) {
        int nrow = nb * 16 + (lane & 15);
        bf16x8 bfr = *(const bf16x8*)&BbT[swz(nrow, c0)];
        accT[nb] = __builtin_amdgcn_mfma_f32_16x16x32_bf16(af, bfr, accT[nb], 0, 0, 0);
      }
    }
    size_t sbase = (((size_t)(b * NH + h)) * 64 + c) * 4096;
#pragma unroll
    for (int nb = 0; nb < 4; ++nb) {
      int n = nb * 16 + (lane & 15);
#pragma unroll
      for (int r = 0; r < 4; ++r) {
        int p = w * 16 + (lane >> 4) * 4 + r;
        stG[sbase + p * 64 + n] = (nbf16)accT[nb][r];
      }
    }
  }
}

// ---------------- inter-chunk scan as MFMA matmul ----------------
// states_in[z] = sum_{j<z} exp(m_z - Q_{j+1}) * st_j   (z=0 row -> zeros)
// grid: bid = ((b*16+h)*16 + et), 512 blocks, 256 threads (4 waves)
__global__ __launch_bounds__(256) void ssd_scan(
    const float* __restrict__ Alast, const nbf16* __restrict__ stG,
    const float* __restrict__ ndecay, nbf16* __restrict__ siG,
    float* __restrict__ nd_in) {
  __shared__ __align__(16) nbf16 Msw[64 * 64];
  __shared__ __align__(16) nbf16 StT[256 * 64];
  __shared__ float Qs[66], mzS[64];
  int tid = threadIdx.x, lane = tid & 63, w = tid >> 6;
  int et = blockIdx.x & 15, h = (blockIdx.x >> 4) & 15, b = blockIdx.x >> 8;

  if (w == 0) {
    float a = Alast[((size_t)(b * NH + h)) * 64 + lane];
    float s = a;
#pragma unroll
    for (int d = 1; d < 64; d <<= 1) {
      float t = __shfl_up(s, d, 64);
      if (lane >= d) s += t;
    }
    float Q = __shfl_up(s, 1, 64);      // Q_z = S_{z-1}, Q_0 = 0
    if (lane == 0) Q = 0.f;
    float m = Q;
#pragma unroll
    for (int d = 1; d < 64; d <<= 1) {
      float t = __shfl_up(m, d, 64);
      if (lane >= d) m = fminf(m, t);
    }
    Qs[lane] = Q; mzS[lane] = m;
    if (lane == 0) { Qs[64] = 0.f; Qs[65] = 0.f; }
  }
  __syncthreads();

  // build M (bf16, swizzled) and stage transposed states
#pragma unroll
  for (int k = 0; k < 16; ++k) {
    int i = tid + (k << 8);
    int z = i >> 6, j = i & 63;
    float v = (j < z) ? expf(mzS[z] - Qs[j + 1]) : 0.f;
    Msw[swz(z, j)] = (nbf16)v;
  }
  size_t stbase = ((size_t)(b * NH + h)) * 64 * 4096 + et * 256;
#pragma unroll
  for (int q = 0; q < 8; ++q) {
    int i = tid + (q << 8);        // 0..2047
    int cc = i >> 5, oct = i & 31; // row c, col chunk
    bf16x8 v = *(const bf16x8*)&stG[stbase + (size_t)cc * 4096 + oct * 8];
#pragma unroll
    for (int jj = 0; jj < 8; ++jj) StT[swz(oct * 8 + jj, cc)] = v[jj];
  }
  __syncthreads();

  // nd_in (et==0 only): f32 from Qs/mz
  if (et == 0 && tid < 64) {
    int z = tid;
    float acc = 0.f;
    for (int j = 0; j < z; ++j)
      acc += expf(mzS[z] - Qs[j + 1]) * ndecay[((size_t)(b * 64 + j)) * 16 + h];
    nd_in[((size_t)(b * 64 + z)) * 16 + h] = acc;
  }

  // out[z][e] = sum_c M[z][c] * StT[e][c]
  f32x4 acc[4][4] = {};
#pragma unroll
  for (int kk = 0; kk < 64; kk += 32) {
    int c0 = kk + (lane >> 4) * 8;
    bf16x8 af[4], bfr[4];
#pragma unroll
    for (int i = 0; i < 4; ++i) {
      af[i]  = *(const bf16x8*)&Msw[swz(i * 16 + (lane & 15), c0)];
      bfr[i] = *(const bf16x8*)&StT[swz(w * 64 + i * 16 + (lane & 15), c0)];
    }
#pragma unroll
    for (int mi = 0; mi < 4; ++mi)
#pragma unroll
      for (int ni = 0; ni < 4; ++ni)
        acc[mi][ni] = __builtin_amdgcn_mfma_f32_16x16x32_bf16(af[mi], bfr[ni], acc[mi][ni], 0, 0, 0);
  }
  size_t obase = ((size_t)(b * NH + h)) * 64 * 4096 + et * 256;
#pragma unroll
  for (int mi = 0; mi < 4; ++mi)
#pragma unroll
    for (int ni = 0; ni < 4; ++ni) {
      int e = w * 64 + ni * 16 + (lane & 15);
#pragma unroll
      for (int r = 0; r < 4; ++r) {
        int z = mi * 16 + (lane >> 4) * 4 + r;
        siG[obase + (size_t)z * 4096 + e] = (nbf16)acc[mi][ni][r];
      }
    }
}

// ---------------- off-diagonal + combine (MFMA), in-place Ydg -> Y bf16 ----------------
__global__ __launch_bounds__(256) void ssd_off(
    const nbf16* __restrict__ xw, const float* __restrict__ cw,
    const float* __restrict__ cb, const nbf16* __restrict__ siG,
    const float* __restrict__ norm_diag, const float* __restrict__ sdo_g,
    const float* __restrict__ nd_in, nbf16* __restrict__ Ydg) {
  __shared__ __align__(16) nbf16 Craw[68 * 64];
  __shared__ __align__(16) nbf16 Ssb[64 * 64];
  int tid = threadIdx.x, lane = tid & 63, w = tid >> 6;
  int h = blockIdx.x & 15, c = (blockIdx.x >> 4) & 63, b = blockIdx.x >> 10;

  for (int i = tid; i < 67 * 8; i += 256) {
    int row = i >> 3, n0 = (i & 7) * 8;
    int t = c * 64 - 3 + row;
    bf16x8 v = {};
    if (t >= 0) v = *(const bf16x8*)(xw + ((size_t)(b * SEQL + t)) * DPROJ + h * 64 + n0);
    *(bf16x8*)&Craw[swz(row, n0)] = v;
  }
  {
    size_t sbase = (((size_t)(b * NH + h)) * 64 + c) * 4096;
    for (int i = tid; i < 512; i += 256) {
      int p = i >> 3, n0 = (i & 7) * 8;
      bf16x8 v = *(const bf16x8*)&siG[sbase + p * 64 + n0];
      *(bf16x8*)&Ssb[swz(p, n0)] = v;
    }
  }
  __syncthreads();

  float rc[16];
  {
    int n = tid & 63, base = tid >> 6;
    const float* wcc = cw + (size_t)(h * 64 + n) * 4;
    float bcc = cb[h * 64 + n];
#pragma unroll
    for (int q = 0; q < 16; ++q) {
      int l = base + q * 4;
      float aC = bcc;
#pragma unroll
      for (int d = 0; d < 4; ++d) aC = fmaf((float)Craw[swz(l + d, n)], wcc[d], aC);
      rc[q] = aC;
    }
  }
  __syncthreads();
  {
    int n = tid & 63, base = tid >> 6;
#pragma unroll
    for (int q = 0; q < 16; ++q) Craw[swz(base + q * 4, n)] = (nbf16)rc[q];
  }
  __syncthreads();

  f32x4 accO[4] = {};
#pragma unroll
  for (int kk = 0; kk < 64; kk += 32) {
    int arow = w * 16 + (lane & 15);
    int c0 = kk + (lane >> 4) * 8;
    bf16x8 af = *(const bf16x8*)&Craw[swz(arow, c0)];
#pragma unroll
    for (int pb = 0; pb < 4; ++pb) {
      int prow = pb * 16 + (lane & 15);
      bf16x8 bfr = *(const bf16x8*)&Ssb[swz(prow, c0)];
      accO[pb] = __builtin_amdgcn_mfma_f32_16x16x32_bf16(af, bfr, accO[pb], 0, 0, 0);
    }
  }
  float ndin = nd_in[blockIdx.x];
  size_t ybase = ((size_t)(b * SEQL + c * 64)) * DMODEL + h * 64;
#pragma unroll
  for (int r = 0; r < 4; ++r) {
    int l = w * 16 + (lane >> 4) * 4 + r;
    float sd = sdo_g[(size_t)blockIdx.x * 64 + l];
    float nrm = norm_diag[(size_t)blockIdx.x * 64 + l] + ndin * sd;
#pragma unroll
    for (int pb = 0; pb < 4; ++pb) {
      int p = pb * 16 + (lane & 15);
      size_t yi = ybase + (size_t)l * DMODEL + p;
      Ydg[yi] = (nbf16)(((float)Ydg[yi] + accO[pb][r] * sd) / nrm);
    }
  }
}

extern "C" void kernel_launch(void* const* d_in, const int* in_sizes, int n_in,
                              void* d_out, int out_size, void* d_ws, size_t ws_size,
                              hipStream_t stream) {
  const float* x          = (const float*)d_in[0];
  const float* in_proj_w  = (const float*)d_in[1];
  const float* conv_w     = (const float*)d_in[2];
  const float* conv_b     = (const float*)d_in[3];
  const float* w_base     = (const float*)d_in[4];
  const float* out_proj_w = (const float*)d_in[5];
  float* out = (float*)d_out;

  char* ws = (char*)d_ws;
  size_t off = 0;
  auto alloc = [&](size_t bytes) {
    void* p = ws + off;
    off += (bytes + 255) & ~(size_t)255;
    return p;
  };
  const size_t BT = (size_t)2 * SEQL;                        // 8192
  nbf16* xIOw = (nbf16*)alloc(BT * DPROJ * 2);               // 50.6 MB
  nbf16* xbf  = (nbf16*)alloc(BT * DMODEL * 2);              // 16.8 MB (reused as Ydg/Y)
  nbf16* wibf = (nbf16*)alloc((size_t)3200 * 1024 * 2);      // 6.6 MB
  nbf16* wobf = (nbf16*)alloc((size_t)1024 * 1024 * 2);      // 2.1 MB
  nbf16* stG  = (nbf16*)alloc((size_t)2048 * 4096 * 2);      // 16.8 MB
  nbf16* siG  = (nbf16*)alloc((size_t)2048 * 4096 * 2);      // 16.8 MB
  float* norm_diag = (float*)alloc((size_t)2048 * 64 * 4);
  float* sdo   = (float*)alloc((size_t)2048 * 64 * 4);
  float* ndec  = (float*)alloc((size_t)2048 * 4);
  float* Alast = (float*)alloc((size_t)2048 * 4);
  float* nd_in = (float*)alloc((size_t)2048 * 4);
  nbf16* Ydg = xbf;   // xbf dead after in-proj GEMM; Ydg updated in place by ssd_off

  cast_bf16<<<(int)(BT * DMODEL / 4 / 256), 256, 0, stream>>>(x, xbf, BT * DMODEL);
  cast_pad_w<<<3200 * 1024 / 4 / 256, 256, 0, stream>>>(in_proj_w, wibf);
  cast_bf16<<<DMODEL * DMODEL / 4 / 256, 256, 0, stream>>>(out_proj_w, wobf, (long)DMODEL * DMODEL);
  // in-proj: M=8192, Npad=3200 -> grid 25 x 32 (800 blocks, %8==0)
  gemm_mfma<nbf16><<<dim3(25, BT / 256), 512, 0, stream>>>(
      xbf, wibf, xIOw, (int)BT, DPROJ, DMODEL);
  ssd_intra<<<2048, 256, 0, stream>>>(xIOw, conv_w, conv_b, w_base,
                                      Ydg, stG, norm_diag, sdo, ndec, Alast);
  ssd_scan<<<512, 256, 0, stream>>>(Alast, stG, ndec, siG, nd_in);
  ssd_off<<<2048, 256, 0, stream>>>(xIOw, conv_w, conv_b, siG,
                                    norm_diag, sdo, nd_in, Ydg);
  // out-proj: grid 8 x 32 (256 blocks)
  gemm_mfma<float><<<dim3(DMODEL / 128, BT / 256), 512, 0, stream>>>(
      Ydg, wobf, out, (int)BT, DMODEL, DMODEL);
}

// Round 7
// 290.960 us; speedup vs baseline: 5.8486x; 1.0375x over previous
//
#include <hip/hip_runtime.h>
#include <hip/hip_bf16.h>
#include <math.h>
#include <stdint.h>

#define SEQL 4096
#define NH 16
#define CDIM 3072
#define DPROJ 3088
#define DMODEL 1024

typedef __bf16 nbf16;
typedef __attribute__((ext_vector_type(8))) __bf16 bf16x8;
typedef __attribute__((ext_vector_type(4))) float f32x4;

__device__ inline void store_val(float* p, float v) { *p = v; }
__device__ inline void store_val(nbf16* p, float v) { *p = (nbf16)v; }

__device__ __forceinline__ void gload_lds16(const void* g, void* l) {
  __builtin_amdgcn_global_load_lds(
      (const __attribute__((address_space(1))) void*)g,
      (__attribute__((address_space(3))) void*)l, 16, 0, 0);
}

// swizzled bf16 LDS index for [R][64] row-major tiles (16B-slot XOR)
__device__ __forceinline__ int swz(int row, int col) {
  return row * 64 + (col ^ ((row & 7) << 3));
}

// ---------------- bf16 MFMA GEMM: C[M,N] = A[M,K] @ B[N,K]^T ----------------
// 128x128 tile, 4 waves (2x2), 64x64/wave, BK=64, double-buffered LDS with
// early-issued prefetch (T3-minimum) + T2 both-sides swizzle:
//   LDS dest linear (gload_lds requirement), global SOURCE slot pre-swizzled,
//   fragment reads XOR-swizzled -> conflict-free ds_read_b128.
template <typename TOUT>
__global__ __launch_bounds__(256) void gemm_mfma(const nbf16* __restrict__ A,
                                                 const nbf16* __restrict__ B,
                                                 TOUT* __restrict__ C,
                                                 int M, int N, int K) {
  __shared__ __align__(16) nbf16 Alds[2][128 * 64];
  __shared__ __align__(16) nbf16 Blds[2][128 * 64];
  int tid = threadIdx.x;
  int lane = tid & 63;
  int w = tid >> 6, wm = w >> 1, wn = w & 1;
  // T1 bijective XCD swizzle (nwg % 8 == 0)
  int gx = gridDim.x;
  int nwg = gx * gridDim.y;
  int orig = blockIdx.y * gx + blockIdx.x;
  int wg = (orig & 7) * (nwg >> 3) + (orig >> 3);
  int bm = (wg / gx) * 128, bn = (wg % gx) * 128;
  const nbf16* Ag = A + (size_t)bm * K;
  const nbf16* Bg = B + (size_t)bn * K;
  f32x4 acc[4][4] = {};
  const int nt = K >> 6;

  // stage one 128x64 K-tile pair into buf; source slot pre-swizzled so that
  // LDS slot cs holds global slot cs^(row&7)
  auto STAGE = [&](int buf, int k0) {
#pragma unroll
    for (int q = 0; q < 4; ++q) {
      int e = (q * 256 + tid) * 8;
      int row = e >> 6;
      int cs = (e >> 3) & 7;
      int sc = (cs ^ (row & 7)) << 3;
      gload_lds16(Ag + (size_t)row * K + k0 + sc, &Alds[buf][e]);
      gload_lds16(Bg + (size_t)row * K + k0 + sc, &Blds[buf][e]);
    }
  };
  auto COMPUTE = [&](int buf) {
#pragma unroll
    for (int kk = 0; kk < 64; kk += 32) {
      bf16x8 af[4], bfr[4];
      int col = kk + (lane >> 4) * 8;
#pragma unroll
      for (int i = 0; i < 4; ++i) {
        af[i]  = *(const bf16x8*)&Alds[buf][swz(wm * 64 + i * 16 + (lane & 15), col)];
        bfr[i] = *(const bf16x8*)&Blds[buf][swz(wn * 64 + i * 16 + (lane & 15), col)];
      }
#pragma unroll
      for (int mi = 0; mi < 4; ++mi)
#pragma unroll
        for (int ni = 0; ni < 4; ++ni)
          acc[mi][ni] = __builtin_amdgcn_mfma_f32_16x16x32_bf16(af[mi], bfr[ni], acc[mi][ni], 0, 0, 0);
    }
  };

  STAGE(0, 0);
  asm volatile("s_waitcnt vmcnt(0)" ::: "memory");
  __builtin_amdgcn_s_barrier();
  for (int t = 0; t < nt - 1; ++t) {
    int cur = t & 1;
    STAGE(cur ^ 1, (t + 1) << 6);   // issue next-tile loads FIRST
    COMPUTE(cur);                   // ~700cy of ds_read+MFMA hides them
    asm volatile("s_waitcnt vmcnt(0)" ::: "memory");
    __builtin_amdgcn_s_barrier();
  }
  COMPUTE((nt - 1) & 1);

#pragma unroll
  for (int mi = 0; mi < 4; ++mi)
#pragma unroll
    for (int ni = 0; ni < 4; ++ni) {
      int colw = bn + wn * 64 + ni * 16 + (lane & 15);
      if (colw >= N) continue;
#pragma unroll
      for (int j = 0; j < 4; ++j) {
        int roww = bm + wm * 64 + mi * 16 + (lane >> 4) * 4 + j;
        store_val(&C[(size_t)roww * N + colw], acc[mi][ni][j]);
      }
    }
}

// ---------------- f32 -> bf16 casts ----------------
__global__ __launch_bounds__(256) void cast_bf16(const float* __restrict__ in,
                                                 nbf16* __restrict__ out, long n) {
  long i = ((long)blockIdx.x * 256 + threadIdx.x) * 4;
  if (i >= n) return;
  float4 v = *(const float4*)(in + i);
  out[i] = (nbf16)v.x; out[i + 1] = (nbf16)v.y;
  out[i + 2] = (nbf16)v.z; out[i + 3] = (nbf16)v.w;
}

__global__ __launch_bounds__(256) void cast_pad_w(const float* __restrict__ in,
                                                  nbf16* __restrict__ out) {
  long i = ((long)blockIdx.x * 256 + threadIdx.x) * 4;
  if (i >= (long)3200 * 1024) return;
  int row = (int)(i >> 10);
  if (row < DPROJ) {
    float4 v = *(const float4*)(in + i);
    out[i] = (nbf16)v.x; out[i + 1] = (nbf16)v.y;
    out[i + 2] = (nbf16)v.z; out[i + 3] = (nbf16)v.w;
  } else {
    out[i] = (nbf16)0.f; out[i + 1] = (nbf16)0.f;
    out[i + 2] = (nbf16)0.f; out[i + 3] = (nbf16)0.f;
  }
}

// ---------------- intra-chunk SSD: conv + scalars + 3 MFMA matmuls ----------------
// grid: bid = b*1024 + c*16 + h (2048 blocks), 256 threads (4 waves)
__global__ __launch_bounds__(256) void ssd_intra(
    const nbf16* __restrict__ xw, const float* __restrict__ cw,
    const float* __restrict__ cb, const float* __restrict__ wbase,
    nbf16* __restrict__ Ydg, nbf16* __restrict__ stG,
    float* __restrict__ norm_diag, float* __restrict__ sdo_g,
    float* __restrict__ ndecay, float* __restrict__ Alast) {
  __shared__ __align__(16) nbf16 Craw[68 * 64];
  __shared__ __align__(16) nbf16 Braw[68 * 64];
  __shared__ __align__(16) nbf16 Xraw[68 * 64];
  __shared__ __align__(16) nbf16 BbT[64 * 64];
  __shared__ __align__(16) nbf16 XbT[64 * 64];
  __shared__ float cums_s[64], mincs_s[64], dec_s[64];
  nbf16* Sb = Xraw;

  int tid = threadIdx.x;
  int lane = tid & 63;
  int w = tid >> 6;
  int h = blockIdx.x & 15;
  int c = (blockIdx.x >> 4) & 63;
  int b = blockIdx.x >> 10;

  for (int i = tid; i < 67 * 8; i += 256) {
    int row = i >> 3, n0 = (i & 7) * 8;
    int t = c * 64 - 3 + row;
    bf16x8 vc = {}, vb = {}, vx = {};
    if (t >= 0) {
      const nbf16* r = xw + ((size_t)(b * SEQL + t)) * DPROJ + h * 64 + n0;
      vc = *(const bf16x8*)(r);
      vb = *(const bf16x8*)(r + 1024);
      vx = *(const bf16x8*)(r + 2048);
    }
    int idx = swz(row, n0);
    *(bf16x8*)&Craw[idx] = vc;
    *(bf16x8*)&Braw[idx] = vb;
    *(bf16x8*)&Xraw[idx] = vx;
  }

  if (w == 0) {
    float a = (float)xw[((size_t)(b * SEQL + c * 64 + lane)) * DPROJ + CDIM + h] * wbase[h];
    float cum = a;
#pragma unroll
    for (int d = 1; d < 64; d <<= 1) {
      float t = __shfl_up(cum, d, 64);
      if (lane >= d) cum += t;
    }
    float mn = cum;
#pragma unroll
    for (int d = 1; d < 64; d <<= 1) {
      float t = __shfl_up(mn, d, 64);
      if (lane >= d) mn = fminf(mn, t);
    }
    float mnall = __shfl(mn, 63, 64);
    float mx = cum;
#pragma unroll
    for (int d = 1; d < 64; d <<= 1) mx = fmaxf(mx, __shfl_xor(mx, d, 64));
    float dec = expf(mnall - cum);
    float sdo = expf(cum - mx);
    float nd = dec;
#pragma unroll
    for (int d = 1; d < 64; d <<= 1) nd += __shfl_xor(nd, d, 64);
    cums_s[lane] = cum; mincs_s[lane] = mn; dec_s[lane] = dec;
    sdo_g[(size_t)blockIdx.x * 64 + lane] = sdo;
    if (lane == 0) ndecay[blockIdx.x] = nd;
    if (lane == 63) Alast[((size_t)(b * NH + h)) * 64 + c] = cum;
  }
  __syncthreads();

  float rc[16], rb[16], rx[16];
  {
    int n = tid & 63, base = tid >> 6;
    const float* wcc = cw + (size_t)(h * 64 + n) * 4;
    const float* wcb = wcc + 4096;
    const float* wcx = wcc + 8192;
    float bcc = cb[h * 64 + n], bcb = cb[1024 + h * 64 + n], bcx = cb[2048 + h * 64 + n];
#pragma unroll
    for (int q = 0; q < 16; ++q) {
      int l = base + q * 4;
      float aC = bcc, aB = bcb, aX = bcx;
#pragma unroll
      for (int d = 0; d < 4; ++d) {
        int idx = swz(l + d, n);
        aC = fmaf((float)Craw[idx], wcc[d], aC);
        aB = fmaf((float)Braw[idx], wcb[d], aB);
        aX = fmaf((float)Xraw[idx], wcx[d], aX);
      }
      rc[q] = aC; rb[q] = aB; rx[q] = aX;
    }
  }
  __syncthreads();
  {
    int n = tid & 63, base = tid >> 6;
#pragma unroll
    for (int q = 0; q < 16; ++q) {
      int l = base + q * 4;
      Craw[swz(l, n)] = (nbf16)rc[q];
      Braw[swz(l, n)] = (nbf16)rb[q];
      BbT[swz(n, l)] = (nbf16)rb[q];
      XbT[swz(n, l)] = (nbf16)rx[q];
    }
  }
  __syncthreads();

  // matmul 1: S[l][s] = (C_l . B_s) * exp(mincs[l]-cums[s]), s<=l
  {
    f32x4 accS[4] = {};
#pragma unroll
    for (int kk = 0; kk < 64; kk += 32) {
      int arow = w * 16 + (lane & 15);
      int c0 = kk + (lane >> 4) * 8;
      bf16x8 af = *(const bf16x8*)&Craw[swz(arow, c0)];
#pragma unroll
      for (int nb = 0; nb < 4; ++nb) {
        int brow = nb * 16 + (lane & 15);
        bf16x8 bfr = *(const bf16x8*)&Braw[swz(brow, c0)];
        accS[nb] = __builtin_amdgcn_mfma_f32_16x16x32_bf16(af, bfr, accS[nb], 0, 0, 0);
      }
    }
    float rowsum[4] = {0.f, 0.f, 0.f, 0.f};
#pragma unroll
    for (int nb = 0; nb < 4; ++nb) {
      int s = nb * 16 + (lane & 15);
      float cs = cums_s[s];
#pragma unroll
      for (int r = 0; r < 4; ++r) {
        int l = w * 16 + (lane >> 4) * 4 + r;
        float e = (s <= l) ? expf(mincs_s[l] - cs) : 0.f;
        rowsum[r] += e;
        Sb[swz(l, s)] = (nbf16)(accS[nb][r] * e);
      }
    }
#pragma unroll
    for (int r = 0; r < 4; ++r) {
#pragma unroll
      for (int d = 1; d < 16; d <<= 1) rowsum[r] += __shfl_xor(rowsum[r], d, 64);
      if ((lane & 15) == 0) {
        int l = w * 16 + (lane >> 4) * 4 + r;
        norm_diag[(size_t)blockIdx.x * 64 + l] = rowsum[r];
      }
    }
  }
  __syncthreads();

  // matmul 2: Y_diag[l][p] = sum_s S[l][s] * X[s][p]  (bf16 out)
  {
    f32x4 accY[4] = {};
#pragma unroll
    for (int kk = 0; kk < 64; kk += 32) {
      int arow = w * 16 + (lane & 15);
      int c0 = kk + (lane >> 4) * 8;
      bf16x8 af = *(const bf16x8*)&Sb[swz(arow, c0)];
#pragma unroll
      for (int pb = 0; pb < 4; ++pb) {
        int prow = pb * 16 + (lane & 15);
        bf16x8 bfr = *(const bf16x8*)&XbT[swz(prow, c0)];
        accY[pb] = __builtin_amdgcn_mfma_f32_16x16x32_bf16(af, bfr, accY[pb], 0, 0, 0);
      }
    }
    size_t ybase = ((size_t)(b * SEQL + c * 64)) * DMODEL + h * 64;
#pragma unroll
    for (int pb = 0; pb < 4; ++pb) {
      int p = pb * 16 + (lane & 15);
#pragma unroll
      for (int r = 0; r < 4; ++r) {
        int l = w * 16 + (lane >> 4) * 4 + r;
        Ydg[ybase + (size_t)l * DMODEL + p] = (nbf16)accY[pb][r];
      }
    }
  }

  // matmul 3: states[p][n] = sum_l dec[l]*X[l][p]*B[l][n]  (bf16 out, [b,h,c,p*64+n])
  {
    f32x4 accT[4] = {};
#pragma unroll
    for (int kk = 0; kk < 64; kk += 32) {
      int prow = w * 16 + (lane & 15);
      int c0 = kk + (lane >> 4) * 8;
      bf16x8 xf = *(const bf16x8*)&XbT[swz(prow, c0)];
      bf16x8 af;
#pragma unroll
      for (int j = 0; j < 8; ++j) af[j] = (nbf16)((float)xf[j] * dec_s[c0 + j]);
#pragma unroll
      for (int nb = 0; nb < 4; ++nb) {
        int nrow = nb * 16 + (lane & 15);
        bf16x8 bfr = *(const bf16x8*)&BbT[swz(nrow, c0)];
        accT[nb] = __builtin_amdgcn_mfma_f32_16x16x32_bf16(af, bfr, accT[nb], 0, 0, 0);
      }
    }
    size_t sbase = (((size_t)(b * NH + h)) * 64 + c) * 4096;
#pragma unroll
    for (int nb = 0; nb < 4; ++nb) {
      int n = nb * 16 + (lane & 15);
#pragma unroll
      for (int r = 0; r < 4; ++r) {
        int p = w * 16 + (lane >> 4) * 4 + r;
        stG[sbase + p * 64 + n] = (nbf16)accT[nb][r];
      }
    }
  }
}

// ---------------- inter-chunk scan as MFMA matmul ----------------
__global__ __launch_bounds__(256) void ssd_scan(
    const float* __restrict__ Alast, const nbf16* __restrict__ stG,
    const float* __restrict__ ndecay, nbf16* __restrict__ siG,
    float* __restrict__ nd_in) {
  __shared__ __align__(16) nbf16 Msw[64 * 64];
  __shared__ __align__(16) nbf16 StT[256 * 64];
  __shared__ float Qs[66], mzS[64];
  int tid = threadIdx.x, lane = tid & 63, w = tid >> 6;
  int et = blockIdx.x & 15, h = (blockIdx.x >> 4) & 15, b = blockIdx.x >> 8;

  if (w == 0) {
    float a = Alast[((size_t)(b * NH + h)) * 64 + lane];
    float s = a;
#pragma unroll
    for (int d = 1; d < 64; d <<= 1) {
      float t = __shfl_up(s, d, 64);
      if (lane >= d) s += t;
    }
    float Q = __shfl_up(s, 1, 64);
    if (lane == 0) Q = 0.f;
    float m = Q;
#pragma unroll
    for (int d = 1; d < 64; d <<= 1) {
      float t = __shfl_up(m, d, 64);
      if (lane >= d) m = fminf(m, t);
    }
    Qs[lane] = Q; mzS[lane] = m;
    if (lane == 0) { Qs[64] = 0.f; Qs[65] = 0.f; }
  }
  __syncthreads();

#pragma unroll
  for (int k = 0; k < 16; ++k) {
    int i = tid + (k << 8);
    int z = i >> 6, j = i & 63;
    float v = (j < z) ? expf(mzS[z] - Qs[j + 1]) : 0.f;
    Msw[swz(z, j)] = (nbf16)v;
  }
  size_t stbase = ((size_t)(b * NH + h)) * 64 * 4096 + et * 256;
#pragma unroll
  for (int q = 0; q < 8; ++q) {
    int i = tid + (q << 8);
    int cc = i >> 5, oct = i & 31;
    bf16x8 v = *(const bf16x8*)&stG[stbase + (size_t)cc * 4096 + oct * 8];
#pragma unroll
    for (int jj = 0; jj < 8; ++jj) StT[swz(oct * 8 + jj, cc)] = v[jj];
  }
  __syncthreads();

  if (et == 0 && tid < 64) {
    int z = tid;
    float acc = 0.f;
    for (int j = 0; j < z; ++j)
      acc += expf(mzS[z] - Qs[j + 1]) * ndecay[((size_t)(b * 64 + j)) * 16 + h];
    nd_in[((size_t)(b * 64 + z)) * 16 + h] = acc;
  }

  f32x4 acc[4][4] = {};
#pragma unroll
  for (int kk = 0; kk < 64; kk += 32) {
    int c0 = kk + (lane >> 4) * 8;
    bf16x8 af[4], bfr[4];
#pragma unroll
    for (int i = 0; i < 4; ++i) {
      af[i]  = *(const bf16x8*)&Msw[swz(i * 16 + (lane & 15), c0)];
      bfr[i] = *(const bf16x8*)&StT[swz(w * 64 + i * 16 + (lane & 15), c0)];
    }
#pragma unroll
    for (int mi = 0; mi < 4; ++mi)
#pragma unroll
      for (int ni = 0; ni < 4; ++ni)
        acc[mi][ni] = __builtin_amdgcn_mfma_f32_16x16x32_bf16(af[mi], bfr[ni], acc[mi][ni], 0, 0, 0);
  }
  size_t obase = ((size_t)(b * NH + h)) * 64 * 4096 + et * 256;
#pragma unroll
  for (int mi = 0; mi < 4; ++mi)
#pragma unroll
    for (int ni = 0; ni < 4; ++ni) {
      int e = w * 64 + ni * 16 + (lane & 15);
#pragma unroll
      for (int r = 0; r < 4; ++r) {
        int z = mi * 16 + (lane >> 4) * 4 + r;
        siG[obase + (size_t)z * 4096 + e] = (nbf16)acc[mi][ni][r];
      }
    }
}

// ---------------- off-diagonal + combine (MFMA), in-place Ydg -> Y bf16 ----------------
__global__ __launch_bounds__(256) void ssd_off(
    const nbf16* __restrict__ xw, const float* __restrict__ cw,
    const float* __restrict__ cb, const nbf16* __restrict__ siG,
    const float* __restrict__ norm_diag, const float* __restrict__ sdo_g,
    const float* __restrict__ nd_in, nbf16* __restrict__ Ydg) {
  __shared__ __align__(16) nbf16 Craw[68 * 64];
  __shared__ __align__(16) nbf16 Ssb[64 * 64];
  int tid = threadIdx.x, lane = tid & 63, w = tid >> 6;
  int h = blockIdx.x & 15, c = (blockIdx.x >> 4) & 63, b = blockIdx.x >> 10;

  for (int i = tid; i < 67 * 8; i += 256) {
    int row = i >> 3, n0 = (i & 7) * 8;
    int t = c * 64 - 3 + row;
    bf16x8 v = {};
    if (t >= 0) v = *(const bf16x8*)(xw + ((size_t)(b * SEQL + t)) * DPROJ + h * 64 + n0);
    *(bf16x8*)&Craw[swz(row, n0)] = v;
  }
  {
    size_t sbase = (((size_t)(b * NH + h)) * 64 + c) * 4096;
    for (int i = tid; i < 512; i += 256) {
      int p = i >> 3, n0 = (i & 7) * 8;
      bf16x8 v = *(const bf16x8*)&siG[sbase + p * 64 + n0];
      *(bf16x8*)&Ssb[swz(p, n0)] = v;
    }
  }
  __syncthreads();

  float rc[16];
  {
    int n = tid & 63, base = tid >> 6;
    const float* wcc = cw + (size_t)(h * 64 + n) * 4;
    float bcc = cb[h * 64 + n];
#pragma unroll
    for (int q = 0; q < 16; ++q) {
      int l = base + q * 4;
      float aC = bcc;
#pragma unroll
      for (int d = 0; d < 4; ++d) aC = fmaf((float)Craw[swz(l + d, n)], wcc[d], aC);
      rc[q] = aC;
    }
  }
  __syncthreads();
  {
    int n = tid & 63, base = tid >> 6;
#pragma unroll
    for (int q = 0; q < 16; ++q) Craw[swz(base + q * 4, n)] = (nbf16)rc[q];
  }
  __syncthreads();

  f32x4 accO[4] = {};
#pragma unroll
  for (int kk = 0; kk < 64; kk += 32) {
    int arow = w * 16 + (lane & 15);
    int c0 = kk + (lane >> 4) * 8;
    bf16x8 af = *(const bf16x8*)&Craw[swz(arow, c0)];
#pragma unroll
    for (int pb = 0; pb < 4; ++pb) {
      int prow = pb * 16 + (lane & 15);
      bf16x8 bfr = *(const bf16x8*)&Ssb[swz(prow, c0)];
      accO[pb] = __builtin_amdgcn_mfma_f32_16x16x32_bf16(af, bfr, accO[pb], 0, 0, 0);
    }
  }
  float ndin = nd_in[blockIdx.x];
  size_t ybase = ((size_t)(b * SEQL + c * 64)) * DMODEL + h * 64;
#pragma unroll
  for (int r = 0; r < 4; ++r) {
    int l = w * 16 + (lane >> 4) * 4 + r;
    float sd = sdo_g[(size_t)blockIdx.x * 64 + l];
    float nrm = norm_diag[(size_t)blockIdx.x * 64 + l] + ndin * sd;
#pragma unroll
    for (int pb = 0; pb < 4; ++pb) {
      int p = pb * 16 + (lane & 15);
      size_t yi = ybase + (size_t)l * DMODEL + p;
      Ydg[yi] = (nbf16)(((float)Ydg[yi] + accO[pb][r] * sd) / nrm);
    }
  }
}

extern "C" void kernel_launch(void* const* d_in, const int* in_sizes, int n_in,
                              void* d_out, int out_size, void* d_ws, size_t ws_size,
                              hipStream_t stream) {
  const float* x          = (const float*)d_in[0];
  const float* in_proj_w  = (const float*)d_in[1];
  const float* conv_w     = (const float*)d_in[2];
  const float* conv_b     = (const float*)d_in[3];
  const float* w_base     = (const float*)d_in[4];
  const float* out_proj_w = (const float*)d_in[5];
  float* out = (float*)d_out;

  char* ws = (char*)d_ws;
  size_t off = 0;
  auto alloc = [&](size_t bytes) {
    void* p = ws + off;
    off += (bytes + 255) & ~(size_t)255;
    return p;
  };
  const size_t BT = (size_t)2 * SEQL;                        // 8192
  nbf16* xIOw = (nbf16*)alloc(BT * DPROJ * 2);               // 50.6 MB
  nbf16* xbf  = (nbf16*)alloc(BT * DMODEL * 2);              // 16.8 MB (reused as Ydg/Y)
  nbf16* wibf = (nbf16*)alloc((size_t)3200 * 1024 * 2);      // 6.6 MB
  nbf16* wobf = (nbf16*)alloc((size_t)1024 * 1024 * 2);      // 2.1 MB
  nbf16* stG  = (nbf16*)alloc((size_t)2048 * 4096 * 2);      // 16.8 MB
  nbf16* siG  = (nbf16*)alloc((size_t)2048 * 4096 * 2);      // 16.8 MB
  float* norm_diag = (float*)alloc((size_t)2048 * 64 * 4);
  float* sdo   = (float*)alloc((size_t)2048 * 64 * 4);
  float* ndec  = (float*)alloc((size_t)2048 * 4);
  float* Alast = (float*)alloc((size_t)2048 * 4);
  float* nd_in = (float*)alloc((size_t)2048 * 4);
  nbf16* Ydg = xbf;   // xbf dead after in-proj GEMM; Ydg updated in place by ssd_off

  cast_bf16<<<(int)(BT * DMODEL / 4 / 256), 256, 0, stream>>>(x, xbf, BT * DMODEL);
  cast_pad_w<<<3200 * 1024 / 4 / 256, 256, 0, stream>>>(in_proj_w, wibf);
  cast_bf16<<<DMODEL * DMODEL / 4 / 256, 256, 0, stream>>>(out_proj_w, wobf, (long)DMODEL * DMODEL);
  // in-proj: grid 25 x 64 (1600 blocks, %8==0)
  gemm_mfma<nbf16><<<dim3(25, BT / 128), 256, 0, stream>>>(
      xbf, wibf, xIOw, (int)BT, DPROJ, DMODEL);
  ssd_intra<<<2048, 256, 0, stream>>>(xIOw, conv_w, conv_b, w_base,
                                      Ydg, stG, norm_diag, sdo, ndec, Alast);
  ssd_scan<<<512, 256, 0, stream>>>(Alast, stG, ndec, siG, nd_in);
  ssd_off<<<2048, 256, 0, stream>>>(xIOw, conv_w, conv_b, siG,
                                    norm_diag, sdo, nd_in, Ydg);
  // out-proj: grid 8 x 64 (512 blocks)
  gemm_mfma<float><<<dim3(DMODEL / 128, BT / 128), 256, 0, stream>>>(
      Ydg, wobf, out, (int)BT, DMODEL, DMODEL);
}